// Round 6
// baseline (496.904 us; speedup 1.0000x reference)
//
#include <hip/hip_runtime.h>
#include <stdint.h>

typedef unsigned short u16;
typedef __bf16 bf16x8 __attribute__((ext_vector_type(8)));
typedef float floatx4 __attribute__((ext_vector_type(4)));

#define N_OBJ    131072
#define L0R      262144
#define L1R      524288
#define L2R      393216
#define TOTI     (L0R + L1R + L2R)   // 1179648

// ---- CSR-path workspace layout (bytes), NEED = 174,605,312 ----
// msg      bf16 [TOTI][64]  @ 0          (150,994,944)  exp(12*y) messages
// wt       bf16 weights^T   @ 150994944  (278,528)
// flag     u8   [N]         @ 151273472  (131,072)
// maxmsg   bf16 [N][64]     @ 151404544  (16,777,216)
// nidx     i32  [TOTI]      @ 168181760  (4,718,592)
// count    i32  [N]         @ 172900352  (524,288)
// offsets  i32  [N]         @ 173424640  (524,288)
// cursor   i32  [N]         @ 173948928  (524,288)
// thrpre   i32  [128*256]   @ 174473216  (131,072)
// blocksum i32  [128]       @ 174604288  (1,024)
// ---- fallback (ws < NEED): round-4 layout, s fp32 [N][64] @0, etc. ----

__device__ __forceinline__ float bf2f(u16 u) {
  union { uint32_t i; float f; } v; v.i = ((uint32_t)u) << 16; return v.f;
}
__device__ __forceinline__ u16 f2bf(float f) {
  union { float f; uint32_t i; } v; v.f = f;
  uint32_t r = (v.i + 0x7FFFu + ((v.i >> 16) & 1u)) >> 16;
  return (u16)r;
}
__device__ __forceinline__ uint4 pack8(const float* sp) {
  float4 f0 = *(const float4*)(sp);
  float4 f1 = *(const float4*)(sp + 4);
  uint4 v;
  v.x = (uint32_t)f2bf(f0.x) | ((uint32_t)f2bf(f0.y) << 16);
  v.y = (uint32_t)f2bf(f0.z) | ((uint32_t)f2bf(f0.w) << 16);
  v.z = (uint32_t)f2bf(f1.x) | ((uint32_t)f2bf(f1.y) << 16);
  v.w = (uint32_t)f2bf(f1.z) | ((uint32_t)f2bf(f1.w) << 16);
  return v;
}
// mish(x) = x*tanh(softplus(x))
__device__ __forceinline__ float mish_f(float x) {
  float t = __expf(fminf(x, 30.f));
  float u = 1.f + t; u = u * u;
  return x * (u - 1.f) / (u + 1.f);
}

// ---------- normalize indices (auto int64/int32) + optional degree count ----------
__global__ __launch_bounds__(256) void norm_kernel(
    const int* __restrict__ r0, const int* __restrict__ r1,
    const int* __restrict__ r2, int* __restrict__ n, int* __restrict__ cnt)
{
  int g = blockIdx.x * 256 + (int)threadIdx.x;   // grid covers TOTI exactly
  const int* src; int off;
  if (g < L0R)              { src = r0; off = g; }
  else if (g < L0R + L1R)   { src = r1; off = g - L0R; }
  else                      { src = r2; off = g - L0R - L1R; }
  int lane = (int)threadIdx.x & 63;
  int probe = src[2 * lane + 1];
  bool i64 = (__ballot(probe == 0) == ~0ull);
  int v = i64 ? src[2 * off] : src[off];
  n[g] = v;
  if (cnt) atomicAdd(&cnt[v], 1);
}

// ---------- prep: fp32 weights -> bf16 W^T ----------
__global__ __launch_bounds__(256) void prep_kernel(
    const float* w0, const float* w1, const float* w2, const float* w3,
    const float* w4, const float* w5, const float* w6, const float* w7,
    u16* __restrict__ wt)
{
  int b = blockIdx.x;
  const float* srcs[8] = {w0, w1, w2, w3, w4, w5, w6, w7};
  const int fi[8]   = {64, 64, 128, 128, 192, 192, 128, 128};
  const int fo[8]   = {64, 64, 128, 128, 192, 192, 128, 64};
  const int boff[9] = {0, 16, 32, 96, 160, 304, 448, 512, 544};
  const int woff[8] = {0, 4096, 8192, 24576, 40960, 77824, 114688, 131072};
  int m = 0;
  #pragma unroll
  for (int j = 0; j < 8; ++j) if (b >= boff[j + 1]) m = j + 1;
  int e = (b - boff[m]) * 256 + (int)threadIdx.x;
  int k = e / fo[m];
  int n = e - k * fo[m];
  wt[woff[m] + n * fi[m] + k] = f2bf(srcs[m][e]);   // wt row n: K-contiguous
}

// ---------- flag objects written by relation 0 ----------
__global__ __launch_bounds__(256) void flag_kernel(
    const int* __restrict__ idx0, unsigned char* __restrict__ flag)
{
  int g = blockIdx.x * 256 + (int)threadIdx.x;   // covers L0R exactly
  flag[idx0[g]] = 1;
}

// ---------- exclusive scan of count[131072]: 128 blocks x 1024 objs ----------
__global__ __launch_bounds__(256) void scan_a(
    const int* __restrict__ count, int* __restrict__ thrpre,
    int* __restrict__ blocksum)
{
  int tid = (int)threadIdx.x, b = blockIdx.x;
  int o = b * 1024 + tid * 4;
  int t = count[o] + count[o + 1] + count[o + 2] + count[o + 3];
  __shared__ int sd[256];
  sd[tid] = t; __syncthreads();
  for (int off = 1; off < 256; off <<= 1) {
    int v = (tid >= off) ? sd[tid - off] : 0;
    __syncthreads();
    sd[tid] += v;
    __syncthreads();
  }
  thrpre[b * 256 + tid] = sd[tid] - t;   // exclusive within block
  if (tid == 255) blocksum[b] = sd[tid];
}
__global__ __launch_bounds__(128) void scan_b(int* __restrict__ blocksum)
{
  int tid = (int)threadIdx.x;
  int t = blocksum[tid];
  __shared__ int sd[128];
  sd[tid] = t; __syncthreads();
  for (int off = 1; off < 128; off <<= 1) {
    int v = (tid >= off) ? sd[tid - off] : 0;
    __syncthreads();
    sd[tid] += v;
    __syncthreads();
  }
  blocksum[tid] = sd[tid] - t;           // exclusive block base
}
__global__ __launch_bounds__(256) void scan_c(
    const int* __restrict__ count, const int* __restrict__ thrpre,
    const int* __restrict__ blocksum, int* __restrict__ offsets,
    int* __restrict__ cursor)
{
  int tid = (int)threadIdx.x, b = blockIdx.x;
  int o = b * 1024 + tid * 4;
  int base = blocksum[b] + thrpre[b * 256 + tid];
  #pragma unroll
  for (int j = 0; j < 4; ++j) {
    offsets[o + j] = base;
    cursor[o + j] = base;
    base += count[o + j];
  }
}

// ---------- matmul phase: acc[NTOUT tiles] = A(g_lds) * W^T ----------
template<int D, int NTOUT>
__device__ __forceinline__ void matmul_phase(
    const u16* __restrict__ wtsrc, u16* w_lds,
    const bf16x8 (&af)[D / 32], floatx4 (&acc)[D / 16],
    int tid, int q, int i)
{
  constexpr int PITCH = D + 8;
  #pragma unroll
  for (int t = 0; t < NTOUT; ++t) acc[t] = (floatx4)0.f;
  #pragma unroll
  for (int ch = 0; ch < NTOUT / 4; ++ch) {
    __syncthreads();   // protect w_lds against previous readers
    for (int c = tid; c < 64 * (D / 8); c += 256) {
      int nr = c / (D / 8), p = c - nr * (D / 8);
      *(uint4*)(&w_lds[nr * PITCH + p * 8]) =
          *(const uint4*)(wtsrc + (size_t)(ch * 64 + nr) * D + p * 8);
    }
    __syncthreads();
    #pragma unroll
    for (int k = 0; k < D / 32; ++k) {
      #pragma unroll
      for (int nt = 0; nt < 4; ++nt) {
        bf16x8 bf = *(const bf16x8*)(&w_lds[(nt * 16 + i) * PITCH + k * 32 + q * 8]);
        acc[ch * 4 + nt] =
            __builtin_amdgcn_mfma_f32_16x16x32_bf16(af[k], bf, acc[ch * 4 + nt], 0, 0, 0);
      }
    }
  }
}

// ---------- fused gather + 2-layer MLP ----------
// MODE 0: relation, CSR: write exp(12*y) bf16 to msg[pos][cc], pos via cursor bump
// MODE 1: update: rows = [maxmsg(bf16) | obj_emb(fp32)] -> fp32 d_out
// MODE 2: relation, fallback: fp32 atomicAdd(exp(12*y)) into sAt[obj][cc]
template<int D, int DOUT, int MODE>
__global__ __launch_bounds__(256, (D >= 192) ? 3 : 4) void mlp_kernel(
    const float* __restrict__ srcE, const u16* __restrict__ srcM,
    const int* __restrict__ idx,
    const u16* __restrict__ rwt, const float* __restrict__ rb,
    const u16* __restrict__ owt, const float* __restrict__ ob,
    float* __restrict__ dstF, float* __restrict__ sAt,
    u16* __restrict__ msg, int* __restrict__ cursor)
{
  constexpr int A = D / 64;
  constexpr int PITCH = D + 8;   // bf16 elems; rows 16B aligned
  constexpr int NT1 = D / 16;
  constexpr int NT2 = DOUT / 16;
  constexpr int KI = D / 32;
  __shared__ alignas(16) u16 g_lds[64 * PITCH];
  __shared__ alignas(16) u16 w_lds[64 * PITCH];
  __shared__ float b1_lds[D];
  __shared__ float b2_lds[DOUT];
  __shared__ int i_lds[64 * A];
  __shared__ int p_lds[64 * A];

  const int tid = threadIdx.x;
  const int wave = tid >> 6;
  const int lane = tid & 63;
  const int q = lane >> 4;
  const int i = lane & 15;
  const int t0 = blockIdx.x * 64;

  for (int c = tid; c < D; c += 256) b1_lds[c] = rb[c];
  for (int c = tid; c < DOUT; c += 256) b2_lds[c] = ob[c];
  if (MODE != 1 && tid < 64 * A) {
    int obj = idx[t0 * A + tid];
    i_lds[tid] = obj;
    if (MODE == 0) p_lds[tid] = atomicAdd(&cursor[obj], 1);
  }

  // stage G: 64 tuples x A entity-rows x 8 chunks of 8 bf16 (fp32 -> bf16)
  for (int c = tid; c < 64 * A * 8; c += 256) {
    int e = c >> 3, p = c & 7;
    int r = e / A, sl = e - r * A;
    uint4 val;
    if (MODE != 1) {
      int obj = idx[(t0 + r) * A + sl];
      val = pack8(srcE + (size_t)obj * 64 + p * 8);
    } else {
      if (sl == 0) val = *(const uint4*)(srcM + (size_t)(t0 + r) * 64 + p * 8);
      else         val = pack8(srcE + (size_t)(t0 + r) * 64 + p * 8);
    }
    *(uint4*)(&g_lds[r * PITCH + sl * 64 + p * 8]) = val;
  }
  __syncthreads();

  floatx4 acc[NT1];
  bf16x8 af[KI];

  // phase 1: H = G @ RW
  #pragma unroll
  for (int k = 0; k < KI; ++k)
    af[k] = *(const bf16x8*)(&g_lds[(wave * 16 + i) * PITCH + k * 32 + q * 8]);
  matmul_phase<D, NT1>(rwt, w_lds, af, acc, tid, q, i);

  // epilogue 1: a2 = g + mish(h) in place (each wave owns its 16 rows)
  #pragma unroll
  for (int t = 0; t < NT1; ++t) {
    #pragma unroll
    for (int r = 0; r < 4; ++r) {
      int row = wave * 16 + q * 4 + r;
      int col = t * 16 + i;
      float h = acc[t][r] + b1_lds[col];
      float g = bf2f(g_lds[row * PITCH + col]);
      g_lds[row * PITCH + col] = f2bf(g + mish_f(h));
    }
  }

  // phase 2: Y = A2 @ OW
  #pragma unroll
  for (int k = 0; k < KI; ++k)
    af[k] = *(const bf16x8*)(&g_lds[(wave * 16 + i) * PITCH + k * 32 + q * 8]);
  matmul_phase<D, NT2>(owt, w_lds, af, acc, tid, q, i);

  // epilogue 2
  #pragma unroll
  for (int t = 0; t < NT2; ++t) {
    #pragma unroll
    for (int r = 0; r < 4; ++r) {
      int row = wave * 16 + q * 4 + r;
      int col = t * 16 + i;
      float y = acc[t][r] + b2_lds[col];
      if (MODE == 0) {
        int slot = col >> 6, cc = col & 63;
        float e = __expf(fminf(12.f * y, 82.f));
        int pos = p_lds[row * A + slot];
        msg[(size_t)pos * 64 + cc] = f2bf(e);
      } else if (MODE == 2) {
        int slot = col >> 6, cc = col & 63;
        int obj = i_lds[row * A + slot];
        atomicAdd(&sAt[(size_t)obj * 64 + cc], __expf(fminf(12.f * y, 82.f)));
      } else {
        dstF[(size_t)(t0 + row) * 64 + col] = y;
      }
    }
  }
}

// ---------- CSR reduce: sum contiguous msg segment per object ----------
__global__ __launch_bounds__(256) void reduce_kernel(
    const u16* __restrict__ msg, const int* __restrict__ count,
    const int* __restrict__ offsets, const unsigned char* __restrict__ flag,
    u16* __restrict__ maxmsg)
{
  int wv = (int)threadIdx.x >> 6, lane = (int)threadIdx.x & 63;
  int o = blockIdx.x * 4 + wv;
  int deg = count[o], start = offsets[o];
  const u16* mp = msg + (size_t)start * 64 + lane;
  float s = 0.f;
  for (int j = 0; j < deg; ++j) s += bf2f(mp[(size_t)j * 64]);
  float add = flag[o] ? 1e-37f : 1e-16f;
  maxmsg[(size_t)o * 64 + lane] = f2bf(__logf(s + add) * (1.f / 12.f));
}

// ---------- fallback finalize from fp32 s ----------
__global__ __launch_bounds__(256) void final_kernel(
    const float* __restrict__ s, const unsigned char* __restrict__ flag,
    u16* __restrict__ maxmsg)
{
  int tid = (int)threadIdx.x;
  int o = blockIdx.x * 64 + (tid >> 2);
  int c0 = (tid & 3) * 16;
  float add = flag[o] ? 1e-37f : 1e-16f;
  const float* sp = s + (size_t)o * 64 + c0;
  u16* mp = maxmsg + (size_t)o * 64 + c0;
  u16 tmp[16];
  #pragma unroll
  for (int j = 0; j < 16; ++j)
    tmp[j] = f2bf(__logf(sp[j] + add) * (1.f / 12.f));
  *(uint4*)(mp)     = *(uint4*)(tmp);
  *(uint4*)(mp + 8) = *(uint4*)(tmp + 8);
}

extern "C" void kernel_launch(void* const* d_in, const int* in_sizes, int n_in,
                              void* d_out, int out_size, void* d_ws, size_t ws_size,
                              hipStream_t stream)
{
  (void)in_sizes; (void)n_in; (void)out_size;
  const float* obj_emb = (const float*)d_in[0];
  const float* r0rb = (const float*)d_in[5];
  const float* r0ob = (const float*)d_in[7];
  const float* r1rb = (const float*)d_in[9];
  const float* r1ob = (const float*)d_in[11];
  const float* r2rb = (const float*)d_in[13];
  const float* r2ob = (const float*)d_in[15];
  const float* urb  = (const float*)d_in[17];
  const float* uob  = (const float*)d_in[19];
  float* out = (float*)d_out;
  char* ws = (char*)d_ws;

  const size_t NEED = 174605312ull;
  if (ws_size >= NEED) {
    // ================= CSR path: no hot atomics =================
    u16* msg           = (u16*)(ws);
    u16* wt            = (u16*)(ws + 150994944ull);
    unsigned char* flg = (unsigned char*)(ws + 151273472ull);
    u16* maxmsg        = (u16*)(ws + 151404544ull);
    int* nidx          = (int*)(ws + 168181760ull);
    int* count         = (int*)(ws + 172900352ull);
    int* offsets       = (int*)(ws + 173424640ull);
    int* cursor        = (int*)(ws + 173948928ull);
    int* thrpre        = (int*)(ws + 174473216ull);
    int* blocksum      = (int*)(ws + 174604288ull);

    hipMemsetAsync(count, 0, N_OBJ * 4, stream);
    hipMemsetAsync(flg, 0, N_OBJ, stream);

    norm_kernel<<<TOTI / 256, 256, 0, stream>>>(
        (const int*)d_in[1], (const int*)d_in[2], (const int*)d_in[3], nidx, count);
    prep_kernel<<<544, 256, 0, stream>>>(
        (const float*)d_in[4], (const float*)d_in[6], (const float*)d_in[8],
        (const float*)d_in[10], (const float*)d_in[12], (const float*)d_in[14],
        (const float*)d_in[16], (const float*)d_in[18], wt);
    flag_kernel<<<L0R / 256, 256, 0, stream>>>(nidx, flg);
    scan_a<<<128, 256, 0, stream>>>(count, thrpre, blocksum);
    scan_b<<<1, 128, 0, stream>>>(blocksum);
    scan_c<<<128, 256, 0, stream>>>(count, thrpre, blocksum, offsets, cursor);

    mlp_kernel<64, 64, 0><<<4096, 256, 0, stream>>>(
        obj_emb, nullptr, nidx, wt + 0, r0rb, wt + 4096, r0ob,
        nullptr, nullptr, msg, cursor);
    mlp_kernel<128, 128, 0><<<4096, 256, 0, stream>>>(
        obj_emb, nullptr, nidx + L0R, wt + 8192, r1rb, wt + 24576, r1ob,
        nullptr, nullptr, msg, cursor);
    mlp_kernel<192, 192, 0><<<2048, 256, 0, stream>>>(
        obj_emb, nullptr, nidx + L0R + L1R, wt + 40960, r2rb, wt + 77824, r2ob,
        nullptr, nullptr, msg, cursor);

    reduce_kernel<<<N_OBJ / 4, 256, 0, stream>>>(msg, count, offsets, flg, maxmsg);

    mlp_kernel<128, 64, 1><<<2048, 256, 0, stream>>>(
        obj_emb, maxmsg, nullptr, wt + 114688, urb, wt + 131072, uob,
        out, nullptr, nullptr, nullptr);
  } else {
    // ================= fallback: round-4 fp32 atomic path =================
    float* s           = (float*)(ws);
    u16* wt            = (u16*)(ws + 33554432ull);
    unsigned char* flg = (unsigned char*)(ws + 33832960ull);
    u16* maxmsg        = (u16*)(ws + 33964032ull);
    int* nidx          = (int*)(ws + 50741248ull);

    hipMemsetAsync(s, 0, 64ull * N_OBJ * 4ull, stream);
    hipMemsetAsync(flg, 0, N_OBJ, stream);

    norm_kernel<<<TOTI / 256, 256, 0, stream>>>(
        (const int*)d_in[1], (const int*)d_in[2], (const int*)d_in[3], nidx, nullptr);
    prep_kernel<<<544, 256, 0, stream>>>(
        (const float*)d_in[4], (const float*)d_in[6], (const float*)d_in[8],
        (const float*)d_in[10], (const float*)d_in[12], (const float*)d_in[14],
        (const float*)d_in[16], (const float*)d_in[18], wt);
    flag_kernel<<<L0R / 256, 256, 0, stream>>>(nidx, flg);

    mlp_kernel<64, 64, 2><<<4096, 256, 0, stream>>>(
        obj_emb, nullptr, nidx, wt + 0, r0rb, wt + 4096, r0ob,
        nullptr, s, nullptr, nullptr);
    mlp_kernel<128, 128, 2><<<4096, 256, 0, stream>>>(
        obj_emb, nullptr, nidx + L0R, wt + 8192, r1rb, wt + 24576, r1ob,
        nullptr, s, nullptr, nullptr);
    mlp_kernel<192, 192, 2><<<2048, 256, 0, stream>>>(
        obj_emb, nullptr, nidx + L0R + L1R, wt + 40960, r2rb, wt + 77824, r2ob,
        nullptr, s, nullptr, nullptr);

    final_kernel<<<N_OBJ / 64, 256, 0, stream>>>(s, flg, maxmsg);

    mlp_kernel<128, 64, 1><<<2048, 256, 0, stream>>>(
        obj_emb, maxmsg, nullptr, wt + 114688, urb, wt + 131072, uob,
        out, nullptr, nullptr, nullptr);
  }
}

// Round 7
// 446.337 us; speedup vs baseline: 1.1133x; 1.1133x over previous
//
#include <hip/hip_runtime.h>
#include <stdint.h>

typedef unsigned short u16;
typedef __bf16 bf16x8 __attribute__((ext_vector_type(8)));
typedef float floatx4 __attribute__((ext_vector_type(4)));

#define N_OBJ    131072
#define L0R      262144
#define L1R      524288
#define L2R      393216
#define TOTI     (L0R + L1R + L2R)   // 1179648

// ---- full path layout (bytes), NEED2 = 191,382,528 ----
// msg      bf16 [TOTI][64]  @ 0          (150,994,944)
// wt       bf16 weights^T   @ 150994944  (278,528)
// flag     u8   [N]         @ 151273472  (131,072)
// maxmsg   bf16 [N][64]     @ 151404544  (16,777,216)
// nidx     i32  [TOTI]      @ 168181760  (4,718,592)
// count    i32  [N]         @ 172900352  (524,288)
// offsets  i32  [N]         @ 173424640  (524,288)
// cursor   i32  [N]         @ 173948928  (524,288)
// thrpre   i32  [32768]     @ 174473216  (131,072)
// blocksum i32  [128]       @ 174604288  (1,024 -> pad to 174605312)
// ebf      bf16 [N][64]     @ 174605312  (16,777,216)
// mid path (ws >= 174,605,312): same minus ebf (EBF=0)
// fallback (<174.6MB): s fp32 [N][64] @0; wt @33554432; flag @33832960;
//                      maxmsg @33964032; nidx @50741248

__device__ __forceinline__ float bf2f(u16 u) {
  union { uint32_t i; float f; } v; v.i = ((uint32_t)u) << 16; return v.f;
}
__device__ __forceinline__ u16 f2bf(float f) {
  union { float f; uint32_t i; } v; v.f = f;
  uint32_t r = (v.i + 0x7FFFu + ((v.i >> 16) & 1u)) >> 16;
  return (u16)r;
}
__device__ __forceinline__ uint4 pack8(const float* sp) {
  float4 f0 = *(const float4*)(sp);
  float4 f1 = *(const float4*)(sp + 4);
  uint4 v;
  v.x = (uint32_t)f2bf(f0.x) | ((uint32_t)f2bf(f0.y) << 16);
  v.y = (uint32_t)f2bf(f0.z) | ((uint32_t)f2bf(f0.w) << 16);
  v.z = (uint32_t)f2bf(f1.x) | ((uint32_t)f2bf(f1.y) << 16);
  v.w = (uint32_t)f2bf(f1.z) | ((uint32_t)f2bf(f1.w) << 16);
  return v;
}
__device__ __forceinline__ float mish_f(float x) {
  float t = __expf(fminf(x, 30.f));
  float u = 1.f + t; u = u * u;
  return x * (u - 1.f) / (u + 1.f);
}

// ---------- obj_emb fp32 -> bf16 once ----------
__global__ __launch_bounds__(256) void ebf_kernel(
    const float* __restrict__ src, u16* __restrict__ dst)
{
  size_t g = (size_t)blockIdx.x * 256 + threadIdx.x;   // one 8-elem chunk each
  *(uint4*)(dst + g * 8) = pack8(src + g * 8);
}

// ---------- normalize indices (auto int64/int32) + optional degree count ----------
__global__ __launch_bounds__(256) void norm_kernel(
    const int* __restrict__ r0, const int* __restrict__ r1,
    const int* __restrict__ r2, int* __restrict__ n, int* __restrict__ cnt)
{
  int g = blockIdx.x * 256 + (int)threadIdx.x;   // grid covers TOTI exactly
  const int* src; int off;
  if (g < L0R)              { src = r0; off = g; }
  else if (g < L0R + L1R)   { src = r1; off = g - L0R; }
  else                      { src = r2; off = g - L0R - L1R; }
  int lane = (int)threadIdx.x & 63;
  int probe = src[2 * lane + 1];
  bool i64 = (__ballot(probe == 0) == ~0ull);
  int v = i64 ? src[2 * off] : src[off];
  n[g] = v;
  if (cnt) atomicAdd(&cnt[v], 1);
}

// ---------- prep: fp32 weights -> bf16 W^T ----------
__global__ __launch_bounds__(256) void prep_kernel(
    const float* w0, const float* w1, const float* w2, const float* w3,
    const float* w4, const float* w5, const float* w6, const float* w7,
    u16* __restrict__ wt)
{
  int b = blockIdx.x;
  const float* srcs[8] = {w0, w1, w2, w3, w4, w5, w6, w7};
  const int fi[8]   = {64, 64, 128, 128, 192, 192, 128, 128};
  const int fo[8]   = {64, 64, 128, 128, 192, 192, 128, 64};
  const int boff[9] = {0, 16, 32, 96, 160, 304, 448, 512, 544};
  const int woff[8] = {0, 4096, 8192, 24576, 40960, 77824, 114688, 131072};
  int m = 0;
  #pragma unroll
  for (int j = 0; j < 8; ++j) if (b >= boff[j + 1]) m = j + 1;
  int e = (b - boff[m]) * 256 + (int)threadIdx.x;
  int k = e / fo[m];
  int n = e - k * fo[m];
  wt[woff[m] + n * fi[m] + k] = f2bf(srcs[m][e]);   // wt row n: K-contiguous
}

__global__ __launch_bounds__(256) void flag_kernel(
    const int* __restrict__ idx0, unsigned char* __restrict__ flag)
{
  int g = blockIdx.x * 256 + (int)threadIdx.x;   // covers L0R exactly
  flag[idx0[g]] = 1;
}

// ---------- exclusive scan of count[131072] ----------
__global__ __launch_bounds__(256) void scan_a(
    const int* __restrict__ count, int* __restrict__ thrpre,
    int* __restrict__ blocksum)
{
  int tid = (int)threadIdx.x, b = blockIdx.x;
  int o = b * 1024 + tid * 4;
  int t = count[o] + count[o + 1] + count[o + 2] + count[o + 3];
  __shared__ int sd[256];
  sd[tid] = t; __syncthreads();
  for (int off = 1; off < 256; off <<= 1) {
    int v = (tid >= off) ? sd[tid - off] : 0;
    __syncthreads();
    sd[tid] += v;
    __syncthreads();
  }
  thrpre[b * 256 + tid] = sd[tid] - t;
  if (tid == 255) blocksum[b] = sd[tid];
}
__global__ __launch_bounds__(128) void scan_b(int* __restrict__ blocksum)
{
  int tid = (int)threadIdx.x;
  int t = blocksum[tid];
  __shared__ int sd[128];
  sd[tid] = t; __syncthreads();
  for (int off = 1; off < 128; off <<= 1) {
    int v = (tid >= off) ? sd[tid - off] : 0;
    __syncthreads();
    sd[tid] += v;
    __syncthreads();
  }
  blocksum[tid] = sd[tid] - t;
}
__global__ __launch_bounds__(256) void scan_c(
    const int* __restrict__ count, const int* __restrict__ thrpre,
    const int* __restrict__ blocksum, int* __restrict__ offsets,
    int* __restrict__ cursor)
{
  int tid = (int)threadIdx.x, b = blockIdx.x;
  int o = b * 1024 + tid * 4;
  int base = blocksum[b] + thrpre[b * 256 + tid];
  #pragma unroll
  for (int j = 0; j < 4; ++j) {
    offsets[o + j] = base;
    cursor[o + j] = base;
    base += count[o + j];
  }
}

// ---------- fused gather + 2-layer MLP, weights-in-registers core ----------
// Each wave owns CT col-tiles (B-frags loaded once per phase into VGPRs from
// L2-hot wt), loops 4 row-tiles reading A-frags from g_lds. 3 barriers total.
// MODE 0: relation, CSR msg write.  MODE 1: update -> d_out fp32.
// MODE 2: relation, fp32 atomicAdd fallback.
template<int D, int DOUT, int MODE, int EBF>
__global__ __launch_bounds__(256, (D >= 192) ? 3 : 4) void mlp_kernel(
    const float* __restrict__ srcF, const u16* __restrict__ srcB,
    const u16* __restrict__ srcM, const int* __restrict__ idx,
    const u16* __restrict__ rwt, const float* __restrict__ rb,
    const u16* __restrict__ owt, const float* __restrict__ ob,
    float* __restrict__ dstF, float* __restrict__ sAt,
    u16* __restrict__ msg, int* __restrict__ cursor)
{
  constexpr int A = D / 64;
  constexpr int PITCH = D + 8;     // bf16 elems; rows 16B aligned
  constexpr int KI = D / 32;
  constexpr int CT1 = D / 64;      // col-tiles per wave, phase 1
  constexpr int CT2 = DOUT / 64;   // col-tiles per wave, phase 2
  __shared__ alignas(16) u16 g_lds[64 * PITCH];
  __shared__ float b1_lds[D];
  __shared__ float b2_lds[DOUT];
  __shared__ int i_lds[64 * A];
  __shared__ int p_lds[64 * A];

  const int tid = threadIdx.x;
  const int wave = tid >> 6;
  const int lane = tid & 63;
  const int q = lane >> 4;
  const int i = lane & 15;
  const int t0 = blockIdx.x * 64;

  for (int c = tid; c < D; c += 256) b1_lds[c] = rb[c];
  for (int c = tid; c < DOUT; c += 256) b2_lds[c] = ob[c];
  if (MODE != 1) {
    for (int c = tid; c < 64 * A; c += 256) {
      int obj = idx[t0 * A + c];
      i_lds[c] = obj;
      if (MODE == 0) p_lds[c] = atomicAdd(&cursor[obj], 1);
    }
  }

  // stage G: 64 tuples x A entity-rows x 8 chunks of 8 bf16
  for (int c = tid; c < 64 * A * 8; c += 256) {
    int e = c >> 3, p = c & 7;
    int r = e / A, sl = e - r * A;
    uint4 val;
    if (MODE != 1) {
      int obj = idx[(t0 + r) * A + sl];
      val = EBF ? *(const uint4*)(srcB + (size_t)obj * 64 + p * 8)
                : pack8(srcF + (size_t)obj * 64 + p * 8);
    } else {
      if (sl == 0) val = *(const uint4*)(srcM + (size_t)(t0 + r) * 64 + p * 8);
      else val = EBF ? *(const uint4*)(srcB + (size_t)(t0 + r) * 64 + p * 8)
                     : pack8(srcF + (size_t)(t0 + r) * 64 + p * 8);
    }
    *(uint4*)(&g_lds[r * PITCH + sl * 64 + p * 8]) = val;
  }
  __syncthreads();

  bf16x8 af[KI];

  // ---- phase 1: H = G @ RW ----
  bf16x8 b1[CT1][KI];
  #pragma unroll
  for (int j = 0; j < CT1; ++j)
    #pragma unroll
    for (int k = 0; k < KI; ++k)
      b1[j][k] = *(const bf16x8*)(rwt +
          (size_t)((wave * CT1 + j) * 16 + i) * D + k * 32 + q * 8);

  floatx4 acc1[4][CT1];
  #pragma unroll
  for (int rt = 0; rt < 4; ++rt)
    #pragma unroll
    for (int j = 0; j < CT1; ++j) acc1[rt][j] = (floatx4)0.f;

  #pragma unroll
  for (int rt = 0; rt < 4; ++rt) {
    #pragma unroll
    for (int k = 0; k < KI; ++k)
      af[k] = *(const bf16x8*)(&g_lds[(rt * 16 + i) * PITCH + k * 32 + q * 8]);
    #pragma unroll
    for (int j = 0; j < CT1; ++j)
      #pragma unroll
      for (int k = 0; k < KI; ++k)
        acc1[rt][j] = __builtin_amdgcn_mfma_f32_16x16x32_bf16(
            af[k], b1[j][k], acc1[rt][j], 0, 0, 0);
  }
  __syncthreads();   // all phase-1 g_lds reads done before epilogue-1 writes

  // ---- epilogue 1: a2 = g + mish(h), in place ----
  #pragma unroll
  for (int rt = 0; rt < 4; ++rt)
    #pragma unroll
    for (int j = 0; j < CT1; ++j) {
      int col = (wave * CT1 + j) * 16 + i;
      #pragma unroll
      for (int r = 0; r < 4; ++r) {
        int row = rt * 16 + q * 4 + r;
        float h = acc1[rt][j][r] + b1_lds[col];
        float g = bf2f(g_lds[row * PITCH + col]);
        g_lds[row * PITCH + col] = f2bf(g + mish_f(h));
      }
    }
  __syncthreads();

  // ---- phase 2: Y = A2 @ OW ----
  bf16x8 b2[CT2][KI];
  #pragma unroll
  for (int j = 0; j < CT2; ++j)
    #pragma unroll
    for (int k = 0; k < KI; ++k)
      b2[j][k] = *(const bf16x8*)(owt +
          (size_t)((wave * CT2 + j) * 16 + i) * D + k * 32 + q * 8);

  floatx4 acc2[4][CT2];
  #pragma unroll
  for (int rt = 0; rt < 4; ++rt)
    #pragma unroll
    for (int j = 0; j < CT2; ++j) acc2[rt][j] = (floatx4)0.f;

  #pragma unroll
  for (int rt = 0; rt < 4; ++rt) {
    #pragma unroll
    for (int k = 0; k < KI; ++k)
      af[k] = *(const bf16x8*)(&g_lds[(rt * 16 + i) * PITCH + k * 32 + q * 8]);
    #pragma unroll
    for (int j = 0; j < CT2; ++j)
      #pragma unroll
      for (int k = 0; k < KI; ++k)
        acc2[rt][j] = __builtin_amdgcn_mfma_f32_16x16x32_bf16(
            af[k], b2[j][k], acc2[rt][j], 0, 0, 0);
  }

  // ---- epilogue 2 ----
  #pragma unroll
  for (int rt = 0; rt < 4; ++rt)
    #pragma unroll
    for (int j = 0; j < CT2; ++j) {
      int col = (wave * CT2 + j) * 16 + i;
      #pragma unroll
      for (int r = 0; r < 4; ++r) {
        int row = rt * 16 + q * 4 + r;
        float y = acc2[rt][j][r] + b2_lds[col];
        if (MODE == 0) {
          int slot = col >> 6, cc = col & 63;
          int pos = p_lds[row * A + slot];
          msg[(size_t)pos * 64 + cc] = f2bf(__expf(fminf(12.f * y, 82.f)));
        } else if (MODE == 2) {
          int slot = col >> 6, cc = col & 63;
          int obj = i_lds[row * A + slot];
          atomicAdd(&sAt[(size_t)obj * 64 + cc], __expf(fminf(12.f * y, 82.f)));
        } else {
          dstF[(size_t)(t0 + row) * 64 + col] = y;
        }
      }
    }
}

// ---------- CSR reduce: sum contiguous msg segment per object ----------
__global__ __launch_bounds__(256) void reduce_kernel(
    const u16* __restrict__ msg, const int* __restrict__ count,
    const int* __restrict__ offsets, const unsigned char* __restrict__ flag,
    u16* __restrict__ maxmsg)
{
  int wv = (int)threadIdx.x >> 6, lane = (int)threadIdx.x & 63;
  int o = blockIdx.x * 4 + wv;
  int deg = count[o], start = offsets[o];
  const u16* mp = msg + (size_t)start * 64 + lane;
  float s = 0.f;
  for (int j = 0; j < deg; ++j) s += bf2f(mp[(size_t)j * 64]);
  float add = flag[o] ? 1e-37f : 1e-16f;
  maxmsg[(size_t)o * 64 + lane] = f2bf(__logf(s + add) * (1.f / 12.f));
}

// ---------- fallback finalize from fp32 s ----------
__global__ __launch_bounds__(256) void final_kernel(
    const float* __restrict__ s, const unsigned char* __restrict__ flag,
    u16* __restrict__ maxmsg)
{
  int tid = (int)threadIdx.x;
  int o = blockIdx.x * 64 + (tid >> 2);
  int c0 = (tid & 3) * 16;
  float add = flag[o] ? 1e-37f : 1e-16f;
  const float* sp = s + (size_t)o * 64 + c0;
  u16* mp = maxmsg + (size_t)o * 64 + c0;
  u16 tmp[16];
  #pragma unroll
  for (int j = 0; j < 16; ++j)
    tmp[j] = f2bf(__logf(sp[j] + add) * (1.f / 12.f));
  *(uint4*)(mp)     = *(uint4*)(tmp);
  *(uint4*)(mp + 8) = *(uint4*)(tmp + 8);
}

extern "C" void kernel_launch(void* const* d_in, const int* in_sizes, int n_in,
                              void* d_out, int out_size, void* d_ws, size_t ws_size,
                              hipStream_t stream)
{
  (void)in_sizes; (void)n_in; (void)out_size;
  const float* obj_emb = (const float*)d_in[0];
  const float* r0rb = (const float*)d_in[5];
  const float* r0ob = (const float*)d_in[7];
  const float* r1rb = (const float*)d_in[9];
  const float* r1ob = (const float*)d_in[11];
  const float* r2rb = (const float*)d_in[13];
  const float* r2ob = (const float*)d_in[15];
  const float* urb  = (const float*)d_in[17];
  const float* uob  = (const float*)d_in[19];
  float* out = (float*)d_out;
  char* ws = (char*)d_ws;

  const size_t NEED1 = 174605312ull;              // CSR without ebf
  const size_t NEED2 = NEED1 + 16777216ull;       // + ebf

  if (ws_size >= NEED1) {
    u16* msg           = (u16*)(ws);
    u16* wt            = (u16*)(ws + 150994944ull);
    unsigned char* flg = (unsigned char*)(ws + 151273472ull);
    u16* maxmsg        = (u16*)(ws + 151404544ull);
    int* nidx          = (int*)(ws + 168181760ull);
    int* count         = (int*)(ws + 172900352ull);
    int* offsets       = (int*)(ws + 173424640ull);
    int* cursor        = (int*)(ws + 173948928ull);
    int* thrpre        = (int*)(ws + 174473216ull);
    int* blocksum      = (int*)(ws + 174604288ull);
    u16* ebf           = (u16*)(ws + 174605312ull);
    bool use_ebf = ws_size >= NEED2;

    hipMemsetAsync(count, 0, N_OBJ * 4, stream);
    hipMemsetAsync(flg, 0, N_OBJ, stream);

    if (use_ebf) ebf_kernel<<<4096, 256, 0, stream>>>(obj_emb, ebf);
    norm_kernel<<<TOTI / 256, 256, 0, stream>>>(
        (const int*)d_in[1], (const int*)d_in[2], (const int*)d_in[3], nidx, count);
    prep_kernel<<<544, 256, 0, stream>>>(
        (const float*)d_in[4], (const float*)d_in[6], (const float*)d_in[8],
        (const float*)d_in[10], (const float*)d_in[12], (const float*)d_in[14],
        (const float*)d_in[16], (const float*)d_in[18], wt);
    flag_kernel<<<L0R / 256, 256, 0, stream>>>(nidx, flg);
    scan_a<<<128, 256, 0, stream>>>(count, thrpre, blocksum);
    scan_b<<<1, 128, 0, stream>>>(blocksum);
    scan_c<<<128, 256, 0, stream>>>(count, thrpre, blocksum, offsets, cursor);

    if (use_ebf) {
      mlp_kernel<64, 64, 0, 1><<<4096, 256, 0, stream>>>(
          obj_emb, ebf, nullptr, nidx, wt + 0, r0rb, wt + 4096, r0ob,
          nullptr, nullptr, msg, cursor);
      mlp_kernel<128, 128, 0, 1><<<4096, 256, 0, stream>>>(
          obj_emb, ebf, nullptr, nidx + L0R, wt + 8192, r1rb, wt + 24576, r1ob,
          nullptr, nullptr, msg, cursor);
      mlp_kernel<192, 192, 0, 1><<<2048, 256, 0, stream>>>(
          obj_emb, ebf, nullptr, nidx + L0R + L1R, wt + 40960, r2rb, wt + 77824, r2ob,
          nullptr, nullptr, msg, cursor);
      reduce_kernel<<<N_OBJ / 4, 256, 0, stream>>>(msg, count, offsets, flg, maxmsg);
      mlp_kernel<128, 64, 1, 1><<<2048, 256, 0, stream>>>(
          obj_emb, ebf, maxmsg, nullptr, wt + 114688, urb, wt + 131072, uob,
          out, nullptr, nullptr, nullptr);
    } else {
      mlp_kernel<64, 64, 0, 0><<<4096, 256, 0, stream>>>(
          obj_emb, nullptr, nullptr, nidx, wt + 0, r0rb, wt + 4096, r0ob,
          nullptr, nullptr, msg, cursor);
      mlp_kernel<128, 128, 0, 0><<<4096, 256, 0, stream>>>(
          obj_emb, nullptr, nullptr, nidx + L0R, wt + 8192, r1rb, wt + 24576, r1ob,
          nullptr, nullptr, msg, cursor);
      mlp_kernel<192, 192, 0, 0><<<2048, 256, 0, stream>>>(
          obj_emb, nullptr, nullptr, nidx + L0R + L1R, wt + 40960, r2rb, wt + 77824, r2ob,
          nullptr, nullptr, msg, cursor);
      reduce_kernel<<<N_OBJ / 4, 256, 0, stream>>>(msg, count, offsets, flg, maxmsg);
      mlp_kernel<128, 64, 1, 0><<<2048, 256, 0, stream>>>(
          obj_emb, nullptr, maxmsg, nullptr, wt + 114688, urb, wt + 131072, uob,
          out, nullptr, nullptr, nullptr);
    }
  } else {
    // ---- fallback: fp32 atomic path ----
    float* s           = (float*)(ws);
    u16* wt            = (u16*)(ws + 33554432ull);
    unsigned char* flg = (unsigned char*)(ws + 33832960ull);
    u16* maxmsg        = (u16*)(ws + 33964032ull);
    int* nidx          = (int*)(ws + 50741248ull);

    hipMemsetAsync(s, 0, 64ull * N_OBJ * 4ull, stream);
    hipMemsetAsync(flg, 0, N_OBJ, stream);

    norm_kernel<<<TOTI / 256, 256, 0, stream>>>(
        (const int*)d_in[1], (const int*)d_in[2], (const int*)d_in[3], nidx, nullptr);
    prep_kernel<<<544, 256, 0, stream>>>(
        (const float*)d_in[4], (const float*)d_in[6], (const float*)d_in[8],
        (const float*)d_in[10], (const float*)d_in[12], (const float*)d_in[14],
        (const float*)d_in[16], (const float*)d_in[18], wt);
    flag_kernel<<<L0R / 256, 256, 0, stream>>>(nidx, flg);

    mlp_kernel<64, 64, 2, 0><<<4096, 256, 0, stream>>>(
        obj_emb, nullptr, nullptr, nidx, wt + 0, r0rb, wt + 4096, r0ob,
        nullptr, s, nullptr, nullptr);
    mlp_kernel<128, 128, 2, 0><<<4096, 256, 0, stream>>>(
        obj_emb, nullptr, nullptr, nidx + L0R, wt + 8192, r1rb, wt + 24576, r1ob,
        nullptr, s, nullptr, nullptr);
    mlp_kernel<192, 192, 2, 0><<<2048, 256, 0, stream>>>(
        obj_emb, nullptr, nullptr, nidx + L0R + L1R, wt + 40960, r2rb, wt + 77824, r2ob,
        nullptr, s, nullptr, nullptr);

    final_kernel<<<N_OBJ / 64, 256, 0, stream>>>(s, flg, maxmsg);

    mlp_kernel<128, 64, 1, 0><<<2048, 256, 0, stream>>>(
        obj_emb, nullptr, maxmsg, nullptr, wt + 114688, urb, wt + 131072, uob,
        out, nullptr, nullptr, nullptr);
  }
}

// Round 8
// 415.953 us; speedup vs baseline: 1.1946x; 1.0730x over previous
//
#include <hip/hip_runtime.h>
#include <stdint.h>

typedef unsigned short u16;
typedef __bf16 bf16x8 __attribute__((ext_vector_type(8)));
typedef float floatx4 __attribute__((ext_vector_type(4)));

#define N_OBJ    131072
#define L0R      262144
#define L1R      524288
#define L2R      393216
#define TOTI     (L0R + L1R + L2R)   // 1179648

// ---- full path layout (bytes), NEED2 = 191,382,528 ----
// msg      bf16 [TOTI][64]  @ 0          (150,994,944)
// wt       bf16 weights^T   @ 150994944  (278,528)
// flag     u8   [N]         @ 151273472  (131,072)
// maxmsg   bf16 [N][64]     @ 151404544  (16,777,216)
// nidx     i32  [TOTI]      @ 168181760  (4,718,592)
// count    i32  [N]         @ 172900352  (524,288)
// offsets  i32  [N]         @ 173424640  (524,288)
// cursor   i32  [N]         @ 173948928  (524,288)
// thrpre   i32  [32768]     @ 174473216  (131,072)
// blocksum i32  [128]       @ 174604288  (1,024 -> pad to 174605312)
// ebf      bf16 [N][64]     @ 174605312  (16,777,216)
// mid path (ws >= 174,605,312): same minus ebf (EBF=0)
// fallback (<174.6MB): s fp32 [N][64] @0; wt @33554432; flag @33832960;
//                      maxmsg @33964032; nidx @50741248

__device__ __forceinline__ float bf2f(u16 u) {
  union { uint32_t i; float f; } v; v.i = ((uint32_t)u) << 16; return v.f;
}
__device__ __forceinline__ u16 f2bf(float f) {
  union { float f; uint32_t i; } v; v.f = f;
  uint32_t r = (v.i + 0x7FFFu + ((v.i >> 16) & 1u)) >> 16;
  return (u16)r;
}
__device__ __forceinline__ uint4 pack8(const float* sp) {
  float4 f0 = *(const float4*)(sp);
  float4 f1 = *(const float4*)(sp + 4);
  uint4 v;
  v.x = (uint32_t)f2bf(f0.x) | ((uint32_t)f2bf(f0.y) << 16);
  v.y = (uint32_t)f2bf(f0.z) | ((uint32_t)f2bf(f0.w) << 16);
  v.z = (uint32_t)f2bf(f1.x) | ((uint32_t)f2bf(f1.y) << 16);
  v.w = (uint32_t)f2bf(f1.z) | ((uint32_t)f2bf(f1.w) << 16);
  return v;
}
__device__ __forceinline__ float mish_f(float x) {
  float t = __expf(fminf(x, 30.f));
  float u = 1.f + t; u = u * u;
  return x * (u - 1.f) / (u + 1.f);
}

// ---------- obj_emb fp32 -> bf16 once ----------
__global__ __launch_bounds__(256) void ebf_kernel(
    const float* __restrict__ src, u16* __restrict__ dst)
{
  size_t g = (size_t)blockIdx.x * 256 + threadIdx.x;   // one 8-elem chunk each
  *(uint4*)(dst + g * 8) = pack8(src + g * 8);
}

// ---------- normalize indices (auto int64/int32) + degree count + rel0 flag ----------
__global__ __launch_bounds__(256) void norm_kernel(
    const int* __restrict__ r0, const int* __restrict__ r1,
    const int* __restrict__ r2, int* __restrict__ n, int* __restrict__ cnt,
    unsigned char* __restrict__ flag)
{
  int g = blockIdx.x * 256 + (int)threadIdx.x;   // grid covers TOTI exactly
  const int* src; int off;
  if (g < L0R)              { src = r0; off = g; }
  else if (g < L0R + L1R)   { src = r1; off = g - L0R; }
  else                      { src = r2; off = g - L0R - L1R; }
  int lane = (int)threadIdx.x & 63;
  int probe = src[2 * lane + 1];
  bool i64 = (__ballot(probe == 0) == ~0ull);
  int v = i64 ? src[2 * off] : src[off];
  n[g] = v;
  if (g < L0R) flag[v] = 1;
  if (cnt) atomicAdd(&cnt[v], 1);
}

// ---------- prep: fp32 weights -> bf16 W^T ----------
__global__ __launch_bounds__(256) void prep_kernel(
    const float* w0, const float* w1, const float* w2, const float* w3,
    const float* w4, const float* w5, const float* w6, const float* w7,
    u16* __restrict__ wt)
{
  int b = blockIdx.x;
  const float* srcs[8] = {w0, w1, w2, w3, w4, w5, w6, w7};
  const int fi[8]   = {64, 64, 128, 128, 192, 192, 128, 128};
  const int fo[8]   = {64, 64, 128, 128, 192, 192, 128, 64};
  const int boff[9] = {0, 16, 32, 96, 160, 304, 448, 512, 544};
  const int woff[8] = {0, 4096, 8192, 24576, 40960, 77824, 114688, 131072};
  int m = 0;
  #pragma unroll
  for (int j = 0; j < 8; ++j) if (b >= boff[j + 1]) m = j + 1;
  int e = (b - boff[m]) * 256 + (int)threadIdx.x;
  int k = e / fo[m];
  int n = e - k * fo[m];
  wt[woff[m] + n * fi[m] + k] = f2bf(srcs[m][e]);   // wt row n: K-contiguous
}

// ---------- exclusive scan of count[131072] ----------
__global__ __launch_bounds__(256) void scan_a(
    const int* __restrict__ count, int* __restrict__ thrpre,
    int* __restrict__ blocksum)
{
  int tid = (int)threadIdx.x, b = blockIdx.x;
  int o = b * 1024 + tid * 4;
  int t = count[o] + count[o + 1] + count[o + 2] + count[o + 3];
  __shared__ int sd[256];
  sd[tid] = t; __syncthreads();
  for (int off = 1; off < 256; off <<= 1) {
    int v = (tid >= off) ? sd[tid - off] : 0;
    __syncthreads();
    sd[tid] += v;
    __syncthreads();
  }
  thrpre[b * 256 + tid] = sd[tid] - t;
  if (tid == 255) blocksum[b] = sd[tid];
}
__global__ __launch_bounds__(128) void scan_b(int* __restrict__ blocksum)
{
  int tid = (int)threadIdx.x;
  int t = blocksum[tid];
  __shared__ int sd[128];
  sd[tid] = t; __syncthreads();
  for (int off = 1; off < 128; off <<= 1) {
    int v = (tid >= off) ? sd[tid - off] : 0;
    __syncthreads();
    sd[tid] += v;
    __syncthreads();
  }
  blocksum[tid] = sd[tid] - t;
}
__global__ __launch_bounds__(256) void scan_c(
    const int* __restrict__ count, const int* __restrict__ thrpre,
    const int* __restrict__ blocksum, int* __restrict__ offsets,
    int* __restrict__ cursor)
{
  int tid = (int)threadIdx.x, b = blockIdx.x;
  int o = b * 1024 + tid * 4;
  int base = blocksum[b] + thrpre[b * 256 + tid];
  #pragma unroll
  for (int j = 0; j < 4; ++j) {
    offsets[o + j] = base;
    cursor[o + j] = base;
    base += count[o + j];
  }
}

// ---------- fused gather + 2-layer MLP, weights-in-registers core ----------
// Each wave owns CT col-tiles (B-frags loaded once per phase into VGPRs from
// L2-hot wt), loops 4 row-tiles reading A-frags from g_lds. 3 barriers total.
// MODE 0: relation, CSR msg write.  MODE 1: update -> d_out fp32.
// MODE 2: relation, fp32 atomicAdd fallback.
template<int D, int DOUT, int MODE, int EBF>
__global__ __launch_bounds__(256, (D >= 192) ? 3 : 4) void mlp_kernel(
    const float* __restrict__ srcF, const u16* __restrict__ srcB,
    const u16* __restrict__ srcM, const int* __restrict__ idx,
    const u16* __restrict__ rwt, const float* __restrict__ rb,
    const u16* __restrict__ owt, const float* __restrict__ ob,
    float* __restrict__ dstF, float* __restrict__ sAt,
    u16* __restrict__ msg, int* __restrict__ cursor)
{
  constexpr int A = D / 64;
  constexpr int PITCH = D + 8;     // bf16 elems; rows 16B aligned
  constexpr int KI = D / 32;
  constexpr int CT1 = D / 64;      // col-tiles per wave, phase 1
  constexpr int CT2 = DOUT / 64;   // col-tiles per wave, phase 2
  __shared__ alignas(16) u16 g_lds[64 * PITCH];
  __shared__ float b1_lds[D];
  __shared__ float b2_lds[DOUT];
  __shared__ int i_lds[64 * A];
  __shared__ int p_lds[64 * A];

  const int tid = threadIdx.x;
  const int wave = tid >> 6;
  const int lane = tid & 63;
  const int q = lane >> 4;
  const int i = lane & 15;
  const int t0 = blockIdx.x * 64;

  for (int c = tid; c < D; c += 256) b1_lds[c] = rb[c];
  for (int c = tid; c < DOUT; c += 256) b2_lds[c] = ob[c];
  if (MODE != 1) {
    for (int c = tid; c < 64 * A; c += 256) {
      int obj = idx[t0 * A + c];
      i_lds[c] = obj;
      if (MODE == 0) p_lds[c] = atomicAdd(&cursor[obj], 1);
    }
  }

  // stage G: 64 tuples x A entity-rows x 8 chunks of 8 bf16
  for (int c = tid; c < 64 * A * 8; c += 256) {
    int e = c >> 3, p = c & 7;
    int r = e / A, sl = e - r * A;
    uint4 val;
    if (MODE != 1) {
      int obj = idx[(t0 + r) * A + sl];
      val = EBF ? *(const uint4*)(srcB + (size_t)obj * 64 + p * 8)
                : pack8(srcF + (size_t)obj * 64 + p * 8);
    } else {
      if (sl == 0) val = *(const uint4*)(srcM + (size_t)(t0 + r) * 64 + p * 8);
      else val = EBF ? *(const uint4*)(srcB + (size_t)(t0 + r) * 64 + p * 8)
                     : pack8(srcF + (size_t)(t0 + r) * 64 + p * 8);
    }
    *(uint4*)(&g_lds[r * PITCH + sl * 64 + p * 8]) = val;
  }
  __syncthreads();

  bf16x8 af[KI];

  // ---- phase 1: H = G @ RW ----
  bf16x8 b1[CT1][KI];
  #pragma unroll
  for (int j = 0; j < CT1; ++j)
    #pragma unroll
    for (int k = 0; k < KI; ++k)
      b1[j][k] = *(const bf16x8*)(rwt +
          (size_t)((wave * CT1 + j) * 16 + i) * D + k * 32 + q * 8);

  floatx4 acc1[4][CT1];
  #pragma unroll
  for (int rt = 0; rt < 4; ++rt)
    #pragma unroll
    for (int j = 0; j < CT1; ++j) acc1[rt][j] = (floatx4)0.f;

  #pragma unroll
  for (int rt = 0; rt < 4; ++rt) {
    #pragma unroll
    for (int k = 0; k < KI; ++k)
      af[k] = *(const bf16x8*)(&g_lds[(rt * 16 + i) * PITCH + k * 32 + q * 8]);
    #pragma unroll
    for (int j = 0; j < CT1; ++j)
      #pragma unroll
      for (int k = 0; k < KI; ++k)
        acc1[rt][j] = __builtin_amdgcn_mfma_f32_16x16x32_bf16(
            af[k], b1[j][k], acc1[rt][j], 0, 0, 0);
  }
  __syncthreads();   // all phase-1 g_lds reads done before epilogue-1 writes

  // ---- epilogue 1: a2 = g + mish(h), in place ----
  #pragma unroll
  for (int rt = 0; rt < 4; ++rt)
    #pragma unroll
    for (int j = 0; j < CT1; ++j) {
      int col = (wave * CT1 + j) * 16 + i;
      #pragma unroll
      for (int r = 0; r < 4; ++r) {
        int row = rt * 16 + q * 4 + r;
        float h = acc1[rt][j][r] + b1_lds[col];
        float g = bf2f(g_lds[row * PITCH + col]);
        g_lds[row * PITCH + col] = f2bf(g + mish_f(h));
      }
    }
  __syncthreads();

  // ---- phase 2: Y = A2 @ OW ----
  bf16x8 b2[CT2][KI];
  #pragma unroll
  for (int j = 0; j < CT2; ++j)
    #pragma unroll
    for (int k = 0; k < KI; ++k)
      b2[j][k] = *(const bf16x8*)(owt +
          (size_t)((wave * CT2 + j) * 16 + i) * D + k * 32 + q * 8);

  floatx4 acc2[4][CT2];
  #pragma unroll
  for (int rt = 0; rt < 4; ++rt)
    #pragma unroll
    for (int j = 0; j < CT2; ++j) acc2[rt][j] = (floatx4)0.f;

  #pragma unroll
  for (int rt = 0; rt < 4; ++rt) {
    #pragma unroll
    for (int k = 0; k < KI; ++k)
      af[k] = *(const bf16x8*)(&g_lds[(rt * 16 + i) * PITCH + k * 32 + q * 8]);
    #pragma unroll
    for (int j = 0; j < CT2; ++j)
      #pragma unroll
      for (int k = 0; k < KI; ++k)
        acc2[rt][j] = __builtin_amdgcn_mfma_f32_16x16x32_bf16(
            af[k], b2[j][k], acc2[rt][j], 0, 0, 0);
  }

  // ---- epilogue 2 ----
  #pragma unroll
  for (int rt = 0; rt < 4; ++rt)
    #pragma unroll
    for (int j = 0; j < CT2; ++j) {
      int col = (wave * CT2 + j) * 16 + i;
      #pragma unroll
      for (int r = 0; r < 4; ++r) {
        int row = rt * 16 + q * 4 + r;
        float y = acc2[rt][j][r] + b2_lds[col];
        if (MODE == 0) {
          int slot = col >> 6, cc = col & 63;
          int pos = p_lds[row * A + slot];
          msg[(size_t)pos * 64 + cc] = f2bf(__expf(fminf(12.f * y, 82.f)));
        } else if (MODE == 2) {
          int slot = col >> 6, cc = col & 63;
          int obj = i_lds[row * A + slot];
          atomicAdd(&sAt[(size_t)obj * 64 + cc], __expf(fminf(12.f * y, 82.f)));
        } else {
          dstF[(size_t)(t0 + row) * 64 + col] = y;
        }
      }
    }
}

// ---------- CSR reduce, vectorized: wave per object, 8 rows x uint4/lane ----------
// lane l: row-group rg=l>>3 handles rows rg, rg+8, ...; cols (l&7)*8 .. +7 as
// one uint4 (8 bf16). Wave covers 8 msgs x 64 cols = 1 KB per iteration.
// Cross row-group combine: 3 xor-shuffles; rg 0 writes 8 cols as uint4.
__global__ __launch_bounds__(256) void reduce_kernel(
    const u16* __restrict__ msg, const int* __restrict__ count,
    const int* __restrict__ offsets, const unsigned char* __restrict__ flag,
    u16* __restrict__ maxmsg)
{
  int wv = (int)threadIdx.x >> 6, lane = (int)threadIdx.x & 63;
  int o = blockIdx.x * 4 + wv;
  int deg = count[o], start = offsets[o];
  int rg = lane >> 3;
  int c8 = (lane & 7) * 8;
  const u16* base = msg + (size_t)start * 64 + c8;
  float s[8] = {0.f, 0.f, 0.f, 0.f, 0.f, 0.f, 0.f, 0.f};
  for (int row = rg; row < deg; row += 8) {
    union { uint4 v; u16 a[8]; } ld;
    ld.v = *(const uint4*)(base + (size_t)row * 64);
    #pragma unroll
    for (int k = 0; k < 8; ++k) s[k] += bf2f(ld.a[k]);
  }
  #pragma unroll
  for (int m = 8; m < 64; m <<= 1)
    #pragma unroll
    for (int k = 0; k < 8; ++k) s[k] += __shfl_xor(s[k], m);
  if (rg == 0) {
    float add = flag[o] ? 1e-37f : 1e-16f;
    u16 tmp[8];
    #pragma unroll
    for (int k = 0; k < 8; ++k)
      tmp[k] = f2bf(__logf(s[k] + add) * (1.f / 12.f));
    *(uint4*)(maxmsg + (size_t)o * 64 + c8) = *(uint4*)tmp;
  }
}

// ---------- fallback finalize from fp32 s ----------
__global__ __launch_bounds__(256) void final_kernel(
    const float* __restrict__ s, const unsigned char* __restrict__ flag,
    u16* __restrict__ maxmsg)
{
  int tid = (int)threadIdx.x;
  int o = blockIdx.x * 64 + (tid >> 2);
  int c0 = (tid & 3) * 16;
  float add = flag[o] ? 1e-37f : 1e-16f;
  const float* sp = s + (size_t)o * 64 + c0;
  u16* mp = maxmsg + (size_t)o * 64 + c0;
  u16 tmp[16];
  #pragma unroll
  for (int j = 0; j < 16; ++j)
    tmp[j] = f2bf(__logf(sp[j] + add) * (1.f / 12.f));
  *(uint4*)(mp)     = *(uint4*)(tmp);
  *(uint4*)(mp + 8) = *(uint4*)(tmp + 8);
}

extern "C" void kernel_launch(void* const* d_in, const int* in_sizes, int n_in,
                              void* d_out, int out_size, void* d_ws, size_t ws_size,
                              hipStream_t stream)
{
  (void)in_sizes; (void)n_in; (void)out_size;
  const float* obj_emb = (const float*)d_in[0];
  const float* r0rb = (const float*)d_in[5];
  const float* r0ob = (const float*)d_in[7];
  const float* r1rb = (const float*)d_in[9];
  const float* r1ob = (const float*)d_in[11];
  const float* r2rb = (const float*)d_in[13];
  const float* r2ob = (const float*)d_in[15];
  const float* urb  = (const float*)d_in[17];
  const float* uob  = (const float*)d_in[19];
  float* out = (float*)d_out;
  char* ws = (char*)d_ws;

  const size_t NEED1 = 174605312ull;              // CSR without ebf
  const size_t NEED2 = NEED1 + 16777216ull;       // + ebf

  if (ws_size >= NEED1) {
    u16* msg           = (u16*)(ws);
    u16* wt            = (u16*)(ws + 150994944ull);
    unsigned char* flg = (unsigned char*)(ws + 151273472ull);
    u16* maxmsg        = (u16*)(ws + 151404544ull);
    int* nidx          = (int*)(ws + 168181760ull);
    int* count         = (int*)(ws + 172900352ull);
    int* offsets       = (int*)(ws + 173424640ull);
    int* cursor        = (int*)(ws + 173948928ull);
    int* thrpre        = (int*)(ws + 174473216ull);
    int* blocksum      = (int*)(ws + 174604288ull);
    u16* ebf           = (u16*)(ws + 174605312ull);
    bool use_ebf = ws_size >= NEED2;

    hipMemsetAsync(count, 0, N_OBJ * 4, stream);
    hipMemsetAsync(flg, 0, N_OBJ, stream);

    if (use_ebf) ebf_kernel<<<4096, 256, 0, stream>>>(obj_emb, ebf);
    norm_kernel<<<TOTI / 256, 256, 0, stream>>>(
        (const int*)d_in[1], (const int*)d_in[2], (const int*)d_in[3],
        nidx, count, flg);
    prep_kernel<<<544, 256, 0, stream>>>(
        (const float*)d_in[4], (const float*)d_in[6], (const float*)d_in[8],
        (const float*)d_in[10], (const float*)d_in[12], (const float*)d_in[14],
        (const float*)d_in[16], (const float*)d_in[18], wt);
    scan_a<<<128, 256, 0, stream>>>(count, thrpre, blocksum);
    scan_b<<<1, 128, 0, stream>>>(blocksum);
    scan_c<<<128, 256, 0, stream>>>(count, thrpre, blocksum, offsets, cursor);

    if (use_ebf) {
      mlp_kernel<64, 64, 0, 1><<<4096, 256, 0, stream>>>(
          obj_emb, ebf, nullptr, nidx, wt + 0, r0rb, wt + 4096, r0ob,
          nullptr, nullptr, msg, cursor);
      mlp_kernel<128, 128, 0, 1><<<4096, 256, 0, stream>>>(
          obj_emb, ebf, nullptr, nidx + L0R, wt + 8192, r1rb, wt + 24576, r1ob,
          nullptr, nullptr, msg, cursor);
      mlp_kernel<192, 192, 0, 1><<<2048, 256, 0, stream>>>(
          obj_emb, ebf, nullptr, nidx + L0R + L1R, wt + 40960, r2rb, wt + 77824, r2ob,
          nullptr, nullptr, msg, cursor);
      reduce_kernel<<<N_OBJ / 4, 256, 0, stream>>>(msg, count, offsets, flg, maxmsg);
      mlp_kernel<128, 64, 1, 1><<<2048, 256, 0, stream>>>(
          obj_emb, ebf, maxmsg, nullptr, wt + 114688, urb, wt + 131072, uob,
          out, nullptr, nullptr, nullptr);
    } else {
      mlp_kernel<64, 64, 0, 0><<<4096, 256, 0, stream>>>(
          obj_emb, nullptr, nullptr, nidx, wt + 0, r0rb, wt + 4096, r0ob,
          nullptr, nullptr, msg, cursor);
      mlp_kernel<128, 128, 0, 0><<<4096, 256, 0, stream>>>(
          obj_emb, nullptr, nullptr, nidx + L0R, wt + 8192, r1rb, wt + 24576, r1ob,
          nullptr, nullptr, msg, cursor);
      mlp_kernel<192, 192, 0, 0><<<2048, 256, 0, stream>>>(
          obj_emb, nullptr, nullptr, nidx + L0R + L1R, wt + 40960, r2rb, wt + 77824, r2ob,
          nullptr, nullptr, msg, cursor);
      reduce_kernel<<<N_OBJ / 4, 256, 0, stream>>>(msg, count, offsets, flg, maxmsg);
      mlp_kernel<128, 64, 1, 0><<<2048, 256, 0, stream>>>(
          obj_emb, nullptr, maxmsg, nullptr, wt + 114688, urb, wt + 131072, uob,
          out, nullptr, nullptr, nullptr);
    }
  } else {
    // ---- fallback: fp32 atomic path ----
    float* s           = (float*)(ws);
    u16* wt            = (u16*)(ws + 33554432ull);
    unsigned char* flg = (unsigned char*)(ws + 33832960ull);
    u16* maxmsg        = (u16*)(ws + 33964032ull);
    int* nidx          = (int*)(ws + 50741248ull);

    hipMemsetAsync(s, 0, 64ull * N_OBJ * 4ull, stream);
    hipMemsetAsync(flg, 0, N_OBJ, stream);

    norm_kernel<<<TOTI / 256, 256, 0, stream>>>(
        (const int*)d_in[1], (const int*)d_in[2], (const int*)d_in[3],
        nidx, nullptr, flg);
    prep_kernel<<<544, 256, 0, stream>>>(
        (const float*)d_in[4], (const float*)d_in[6], (const float*)d_in[8],
        (const float*)d_in[10], (const float*)d_in[12], (const float*)d_in[14],
        (const float*)d_in[16], (const float*)d_in[18], wt);

    mlp_kernel<64, 64, 2, 0><<<4096, 256, 0, stream>>>(
        obj_emb, nullptr, nullptr, nidx, wt + 0, r0rb, wt + 4096, r0ob,
        nullptr, s, nullptr, nullptr);
    mlp_kernel<128, 128, 2, 0><<<4096, 256, 0, stream>>>(
        obj_emb, nullptr, nullptr, nidx + L0R, wt + 8192, r1rb, wt + 24576, r1ob,
        nullptr, s, nullptr, nullptr);
    mlp_kernel<192, 192, 2, 0><<<2048, 256, 0, stream>>>(
        obj_emb, nullptr, nullptr, nidx + L0R + L1R, wt + 40960, r2rb, wt + 77824, r2ob,
        nullptr, s, nullptr, nullptr);

    final_kernel<<<N_OBJ / 64, 256, 0, stream>>>(s, flg, maxmsg);

    mlp_kernel<128, 64, 1, 0><<<2048, 256, 0, stream>>>(
        obj_emb, nullptr, maxmsg, nullptr, wt + 114688, urb, wt + 131072, uob,
        out, nullptr, nullptr, nullptr);
  }
}

// Round 9
// 399.879 us; speedup vs baseline: 1.2426x; 1.0402x over previous
//
#include <hip/hip_runtime.h>
#include <stdint.h>

typedef unsigned short u16;
typedef __bf16 bf16x8 __attribute__((ext_vector_type(8)));
typedef float floatx4 __attribute__((ext_vector_type(4)));

#define N_OBJ    131072
#define L0R      262144
#define L1R      524288
#define L2R      393216
#define TOTI     (L0R + L1R + L2R)   // 1179648

// ---- full path layout (bytes), NEED2 = 191,382,528 ----
// msg      bf16 [TOTI][64]  @ 0          (150,994,944)
// wt       bf16 weights^T   @ 150994944  (278,528)
// flag     u8   [N]         @ 151273472  (131,072)
// (unused) bf16 [N][64]     @ 151404544  (16,777,216)
// nidx     i32  [TOTI]      @ 168181760  (4,718,592)
// count    i32  [N]         @ 172900352  (524,288)
// offsets  i32  [N]         @ 173424640  (524,288)
// cursor   i32  [N]         @ 173948928  (524,288)
// thrpre   i32  [32768]     @ 174473216  (131,072)
// blocksum i32  [128]       @ 174604288  (1,024 -> pad to 174605312)
// ebf      bf16 [N][64]     @ 174605312  (16,777,216)
// fallback (<174.6MB): s fp32 [N][64] @0; wt @33554432; flag @33832960;
//                      maxmsg @33964032; nidx @50741248

__device__ __forceinline__ float bf2f(u16 u) {
  union { uint32_t i; float f; } v; v.i = ((uint32_t)u) << 16; return v.f;
}
__device__ __forceinline__ u16 f2bf(float f) {
  union { float f; uint32_t i; } v; v.f = f;
  uint32_t r = (v.i + 0x7FFFu + ((v.i >> 16) & 1u)) >> 16;
  return (u16)r;
}
__device__ __forceinline__ uint4 pack8(const float* sp) {
  float4 f0 = *(const float4*)(sp);
  float4 f1 = *(const float4*)(sp + 4);
  uint4 v;
  v.x = (uint32_t)f2bf(f0.x) | ((uint32_t)f2bf(f0.y) << 16);
  v.y = (uint32_t)f2bf(f0.z) | ((uint32_t)f2bf(f0.w) << 16);
  v.z = (uint32_t)f2bf(f1.x) | ((uint32_t)f2bf(f1.y) << 16);
  v.w = (uint32_t)f2bf(f1.z) | ((uint32_t)f2bf(f1.w) << 16);
  return v;
}
__device__ __forceinline__ float mish_f(float x) {
  float t = __expf(fminf(x, 30.f));
  float u = 1.f + t; u = u * u;
  return x * (u - 1.f) / (u + 1.f);
}

// ---------- obj_emb fp32 -> bf16 once ----------
__global__ __launch_bounds__(256) void ebf_kernel(
    const float* __restrict__ src, u16* __restrict__ dst)
{
  size_t g = (size_t)blockIdx.x * 256 + threadIdx.x;
  *(uint4*)(dst + g * 8) = pack8(src + g * 8);
}

// ---------- normalize indices + degree count + rel0 flag ----------
__global__ __launch_bounds__(256) void norm_kernel(
    const int* __restrict__ r0, const int* __restrict__ r1,
    const int* __restrict__ r2, int* __restrict__ n, int* __restrict__ cnt,
    unsigned char* __restrict__ flag)
{
  int g = blockIdx.x * 256 + (int)threadIdx.x;
  const int* src; int off;
  if (g < L0R)              { src = r0; off = g; }
  else if (g < L0R + L1R)   { src = r1; off = g - L0R; }
  else                      { src = r2; off = g - L0R - L1R; }
  int lane = (int)threadIdx.x & 63;
  int probe = src[2 * lane + 1];
  bool i64 = (__ballot(probe == 0) == ~0ull);
  int v = i64 ? src[2 * off] : src[off];
  n[g] = v;
  if (g < L0R) flag[v] = 1;
  if (cnt) atomicAdd(&cnt[v], 1);
}

// ---------- prep: fp32 weights -> bf16 W^T ----------
__global__ __launch_bounds__(256) void prep_kernel(
    const float* w0, const float* w1, const float* w2, const float* w3,
    const float* w4, const float* w5, const float* w6, const float* w7,
    u16* __restrict__ wt)
{
  int b = blockIdx.x;
  const float* srcs[8] = {w0, w1, w2, w3, w4, w5, w6, w7};
  const int fi[8]   = {64, 64, 128, 128, 192, 192, 128, 128};
  const int fo[8]   = {64, 64, 128, 128, 192, 192, 128, 64};
  const int boff[9] = {0, 16, 32, 96, 160, 304, 448, 512, 544};
  const int woff[8] = {0, 4096, 8192, 24576, 40960, 77824, 114688, 131072};
  int m = 0;
  #pragma unroll
  for (int j = 0; j < 8; ++j) if (b >= boff[j + 1]) m = j + 1;
  int e = (b - boff[m]) * 256 + (int)threadIdx.x;
  int k = e / fo[m];
  int n = e - k * fo[m];
  wt[woff[m] + n * fi[m] + k] = f2bf(srcs[m][e]);
}

// ---------- exclusive scan of count[131072] ----------
__global__ __launch_bounds__(256) void scan_a(
    const int* __restrict__ count, int* __restrict__ thrpre,
    int* __restrict__ blocksum)
{
  int tid = (int)threadIdx.x, b = blockIdx.x;
  int o = b * 1024 + tid * 4;
  int t = count[o] + count[o + 1] + count[o + 2] + count[o + 3];
  __shared__ int sd[256];
  sd[tid] = t; __syncthreads();
  for (int off = 1; off < 256; off <<= 1) {
    int v = (tid >= off) ? sd[tid - off] : 0;
    __syncthreads();
    sd[tid] += v;
    __syncthreads();
  }
  thrpre[b * 256 + tid] = sd[tid] - t;
  if (tid == 255) blocksum[b] = sd[tid];
}
__global__ __launch_bounds__(128) void scan_b(int* __restrict__ blocksum)
{
  int tid = (int)threadIdx.x;
  int t = blocksum[tid];
  __shared__ int sd[128];
  sd[tid] = t; __syncthreads();
  for (int off = 1; off < 128; off <<= 1) {
    int v = (tid >= off) ? sd[tid - off] : 0;
    __syncthreads();
    sd[tid] += v;
    __syncthreads();
  }
  blocksum[tid] = sd[tid] - t;
}
__global__ __launch_bounds__(256) void scan_c(
    const int* __restrict__ count, const int* __restrict__ thrpre,
    const int* __restrict__ blocksum, int* __restrict__ offsets,
    int* __restrict__ cursor)
{
  int tid = (int)threadIdx.x, b = blockIdx.x;
  int o = b * 1024 + tid * 4;
  int base = blocksum[b] + thrpre[b * 256 + tid];
  #pragma unroll
  for (int j = 0; j < 4; ++j) {
    offsets[o + j] = base;
    cursor[o + j] = base;
    base += count[o + j];
  }
}

// ---------- relation MLP body (CSR msg write), dynamic-LDS carve ----------
template<int D, int DOUT, int EBF>
__device__ __forceinline__ void mlp_body(
    char* smem, const float* __restrict__ srcF, const u16* __restrict__ srcB,
    const int* __restrict__ idx, int bidx,
    const u16* __restrict__ rwt, const float* __restrict__ rb,
    const u16* __restrict__ owt, const float* __restrict__ ob,
    u16* __restrict__ msg, int* __restrict__ cursor)
{
  constexpr int A = D / 64;
  constexpr int PITCH = D + 8;
  constexpr int KI = D / 32;
  constexpr int CT1 = D / 64;
  constexpr int CT2 = DOUT / 64;
  u16*   g_lds  = (u16*)smem;                          // 64*PITCH*2 B
  float* b1_lds = (float*)(smem + 64 * PITCH * 2);     // D*4
  float* b2_lds = b1_lds + D;                          // DOUT*4
  int*   i_lds  = (int*)(b2_lds + DOUT);               // 64*A*4
  int*   p_lds  = i_lds + 64 * A;                      // 64*A*4

  const int tid = threadIdx.x;
  const int wave = tid >> 6;
  const int lane = tid & 63;
  const int q = lane >> 4;
  const int i = lane & 15;
  const int t0 = bidx * 64;

  for (int c = tid; c < D; c += 256) b1_lds[c] = rb[c];
  for (int c = tid; c < DOUT; c += 256) b2_lds[c] = ob[c];
  for (int c = tid; c < 64 * A; c += 256) {
    int obj = idx[t0 * A + c];
    i_lds[c] = obj;
    p_lds[c] = atomicAdd(&cursor[obj], 1);
  }

  for (int c = tid; c < 64 * A * 8; c += 256) {
    int e = c >> 3, p = c & 7;
    int r = e / A, sl = e - r * A;
    int obj = idx[(t0 + r) * A + sl];
    uint4 val = EBF ? *(const uint4*)(srcB + (size_t)obj * 64 + p * 8)
                    : pack8(srcF + (size_t)obj * 64 + p * 8);
    *(uint4*)(&g_lds[r * PITCH + sl * 64 + p * 8]) = val;
  }
  __syncthreads();

  bf16x8 af[KI];

  // phase 1
  bf16x8 b1[CT1][KI];
  #pragma unroll
  for (int j = 0; j < CT1; ++j)
    #pragma unroll
    for (int k = 0; k < KI; ++k)
      b1[j][k] = *(const bf16x8*)(rwt +
          (size_t)((wave * CT1 + j) * 16 + i) * D + k * 32 + q * 8);

  floatx4 acc1[4][CT1];
  #pragma unroll
  for (int rt = 0; rt < 4; ++rt)
    #pragma unroll
    for (int j = 0; j < CT1; ++j) acc1[rt][j] = (floatx4)0.f;

  #pragma unroll
  for (int rt = 0; rt < 4; ++rt) {
    #pragma unroll
    for (int k = 0; k < KI; ++k)
      af[k] = *(const bf16x8*)(&g_lds[(rt * 16 + i) * PITCH + k * 32 + q * 8]);
    #pragma unroll
    for (int j = 0; j < CT1; ++j)
      #pragma unroll
      for (int k = 0; k < KI; ++k)
        acc1[rt][j] = __builtin_amdgcn_mfma_f32_16x16x32_bf16(
            af[k], b1[j][k], acc1[rt][j], 0, 0, 0);
  }
  __syncthreads();

  // epilogue 1
  #pragma unroll
  for (int rt = 0; rt < 4; ++rt)
    #pragma unroll
    for (int j = 0; j < CT1; ++j) {
      int col = (wave * CT1 + j) * 16 + i;
      #pragma unroll
      for (int r = 0; r < 4; ++r) {
        int row = rt * 16 + q * 4 + r;
        float h = acc1[rt][j][r] + b1_lds[col];
        float g = bf2f(g_lds[row * PITCH + col]);
        g_lds[row * PITCH + col] = f2bf(g + mish_f(h));
      }
    }
  __syncthreads();

  // phase 2
  bf16x8 b2[CT2][KI];
  #pragma unroll
  for (int j = 0; j < CT2; ++j)
    #pragma unroll
    for (int k = 0; k < KI; ++k)
      b2[j][k] = *(const bf16x8*)(owt +
          (size_t)((wave * CT2 + j) * 16 + i) * D + k * 32 + q * 8);

  floatx4 acc2[4][CT2];
  #pragma unroll
  for (int rt = 0; rt < 4; ++rt)
    #pragma unroll
    for (int j = 0; j < CT2; ++j) acc2[rt][j] = (floatx4)0.f;

  #pragma unroll
  for (int rt = 0; rt < 4; ++rt) {
    #pragma unroll
    for (int k = 0; k < KI; ++k)
      af[k] = *(const bf16x8*)(&g_lds[(rt * 16 + i) * PITCH + k * 32 + q * 8]);
    #pragma unroll
    for (int j = 0; j < CT2; ++j)
      #pragma unroll
      for (int k = 0; k < KI; ++k)
        acc2[rt][j] = __builtin_amdgcn_mfma_f32_16x16x32_bf16(
            af[k], b2[j][k], acc2[rt][j], 0, 0, 0);
  }

  // epilogue 2: CSR message write
  #pragma unroll
  for (int rt = 0; rt < 4; ++rt)
    #pragma unroll
    for (int j = 0; j < CT2; ++j) {
      int col = (wave * CT2 + j) * 16 + i;
      int slot = col >> 6, cc = col & 63;
      #pragma unroll
      for (int r = 0; r < 4; ++r) {
        int row = rt * 16 + q * 4 + r;
        float y = acc2[rt][j][r] + b2_lds[col];
        int pos = p_lds[row * A + slot];
        msg[(size_t)pos * 64 + cc] = f2bf(__expf(fminf(12.f * y, 82.f)));
      }
    }
}

// ---------- merged relation kernel: one dispatch, 3 block ranges ----------
template<int EBF>
__global__ __launch_bounds__(256, 3) void rel_merged(
    const float* __restrict__ srcF, const u16* __restrict__ ebf,
    const int* __restrict__ nidx, const u16* __restrict__ wt,
    const float* __restrict__ r0rb, const float* __restrict__ r0ob,
    const float* __restrict__ r1rb, const float* __restrict__ r1ob,
    const float* __restrict__ r2rb, const float* __restrict__ r2ob,
    u16* __restrict__ msg, int* __restrict__ cursor)
{
  extern __shared__ char smem[];
  int b = blockIdx.x;
  if (b < 4096)
    mlp_body<64, 64, EBF>(smem, srcF, ebf, nidx, b,
                          wt + 0, r0rb, wt + 4096, r0ob, msg, cursor);
  else if (b < 8192)
    mlp_body<128, 128, EBF>(smem, srcF, ebf, nidx + L0R, b - 4096,
                            wt + 8192, r1rb, wt + 24576, r1ob, msg, cursor);
  else
    mlp_body<192, 192, EBF>(smem, srcF, ebf, nidx + L0R + L1R, b - 8192,
                            wt + 40960, r2rb, wt + 77824, r2ob, msg, cursor);
}

// ---------- fused update kernel: inline CSR logsumexp + MLP -> d_out ----------
template<int EBF>
__global__ __launch_bounds__(256, 4) void upd_fused(
    const float* __restrict__ srcF, const u16* __restrict__ ebf,
    const u16* __restrict__ msg, const int* __restrict__ count,
    const int* __restrict__ offsets, const unsigned char* __restrict__ flag,
    const u16* __restrict__ rwt, const float* __restrict__ rb,
    const u16* __restrict__ owt, const float* __restrict__ ob,
    float* __restrict__ dstF)
{
  constexpr int D = 128, DOUT = 64;
  constexpr int PITCH = D + 8;
  constexpr int KI = D / 32;   // 4
  constexpr int CT1 = 2, CT2 = 1;
  __shared__ alignas(16) u16 g_lds[64 * PITCH];
  __shared__ float b1_lds[D];
  __shared__ float b2_lds[DOUT];

  const int tid = threadIdx.x;
  const int wave = tid >> 6;
  const int lane = tid & 63;
  const int q = lane >> 4;
  const int i = lane & 15;
  const int t0 = blockIdx.x * 64;

  for (int c = tid; c < D; c += 256) b1_lds[c] = rb[c];
  for (int c = tid; c < DOUT; c += 256) b2_lds[c] = ob[c];

  // stage: slot 0 = inline logsumexp over CSR msg segment; slot 1 = obj_emb
  for (int c = tid; c < 64 * 2 * 8; c += 256) {
    int e = c >> 3, p = c & 7;
    int r = e >> 1, sl = e & 1;
    int o = t0 + r;
    if (sl == 0) {
      int deg = count[o], st = offsets[o];
      const u16* bp = msg + (size_t)st * 64 + p * 8;
      float s[8] = {0.f, 0.f, 0.f, 0.f, 0.f, 0.f, 0.f, 0.f};
      for (int j = 0; j < deg; ++j) {
        union { uint4 v; u16 a[8]; } ld;
        ld.v = *(const uint4*)(bp + (size_t)j * 64);
        #pragma unroll
        for (int k = 0; k < 8; ++k) s[k] += bf2f(ld.a[k]);
      }
      float add = flag[o] ? 1e-37f : 1e-16f;
      u16 tmp[8];
      #pragma unroll
      for (int k = 0; k < 8; ++k)
        tmp[k] = f2bf(__logf(s[k] + add) * (1.f / 12.f));
      *(uint4*)(&g_lds[r * PITCH + p * 8]) = *(uint4*)tmp;
    } else {
      uint4 val = EBF ? *(const uint4*)(ebf + (size_t)o * 64 + p * 8)
                      : pack8(srcF + (size_t)o * 64 + p * 8);
      *(uint4*)(&g_lds[r * PITCH + 64 + p * 8]) = val;
    }
  }
  __syncthreads();

  bf16x8 af[KI];

  // phase 1
  bf16x8 b1[CT1][KI];
  #pragma unroll
  for (int j = 0; j < CT1; ++j)
    #pragma unroll
    for (int k = 0; k < KI; ++k)
      b1[j][k] = *(const bf16x8*)(rwt +
          (size_t)((wave * CT1 + j) * 16 + i) * D + k * 32 + q * 8);

  floatx4 acc1[4][CT1];
  #pragma unroll
  for (int rt = 0; rt < 4; ++rt)
    #pragma unroll
    for (int j = 0; j < CT1; ++j) acc1[rt][j] = (floatx4)0.f;

  #pragma unroll
  for (int rt = 0; rt < 4; ++rt) {
    #pragma unroll
    for (int k = 0; k < KI; ++k)
      af[k] = *(const bf16x8*)(&g_lds[(rt * 16 + i) * PITCH + k * 32 + q * 8]);
    #pragma unroll
    for (int j = 0; j < CT1; ++j)
      #pragma unroll
      for (int k = 0; k < KI; ++k)
        acc1[rt][j] = __builtin_amdgcn_mfma_f32_16x16x32_bf16(
            af[k], b1[j][k], acc1[rt][j], 0, 0, 0);
  }
  __syncthreads();

  // epilogue 1
  #pragma unroll
  for (int rt = 0; rt < 4; ++rt)
    #pragma unroll
    for (int j = 0; j < CT1; ++j) {
      int col = (wave * CT1 + j) * 16 + i;
      #pragma unroll
      for (int r = 0; r < 4; ++r) {
        int row = rt * 16 + q * 4 + r;
        float h = acc1[rt][j][r] + b1_lds[col];
        float g = bf2f(g_lds[row * PITCH + col]);
        g_lds[row * PITCH + col] = f2bf(g + mish_f(h));
      }
    }
  __syncthreads();

  // phase 2
  bf16x8 b2[CT2][KI];
  #pragma unroll
  for (int j = 0; j < CT2; ++j)
    #pragma unroll
    for (int k = 0; k < KI; ++k)
      b2[j][k] = *(const bf16x8*)(owt +
          (size_t)((wave * CT2 + j) * 16 + i) * D + k * 32 + q * 8);

  floatx4 acc2[4][CT2];
  #pragma unroll
  for (int rt = 0; rt < 4; ++rt)
    #pragma unroll
    for (int j = 0; j < CT2; ++j) acc2[rt][j] = (floatx4)0.f;

  #pragma unroll
  for (int rt = 0; rt < 4; ++rt) {
    #pragma unroll
    for (int k = 0; k < KI; ++k)
      af[k] = *(const bf16x8*)(&g_lds[(rt * 16 + i) * PITCH + k * 32 + q * 8]);
    #pragma unroll
    for (int j = 0; j < CT2; ++j)
      #pragma unroll
      for (int k = 0; k < KI; ++k)
        acc2[rt][j] = __builtin_amdgcn_mfma_f32_16x16x32_bf16(
            af[k], b2[j][k], acc2[rt][j], 0, 0, 0);
  }

  #pragma unroll
  for (int rt = 0; rt < 4; ++rt) {
    int col = wave * 16 + i;
    #pragma unroll
    for (int r = 0; r < 4; ++r) {
      int row = rt * 16 + q * 4 + r;
      dstF[(size_t)(t0 + row) * 64 + col] = acc2[0][0][r * 0 + 0] * 0.f
          + acc2[rt][0][r] + b2_lds[col];
    }
  }
}

// ================= fallback kernels (fp32 atomic path) =================
template<int D, int DOUT, int MODE>
__global__ __launch_bounds__(256, (D >= 192) ? 3 : 4) void mlp_fb(
    const float* __restrict__ srcF, const u16* __restrict__ srcM,
    const int* __restrict__ idx,
    const u16* __restrict__ rwt, const float* __restrict__ rb,
    const u16* __restrict__ owt, const float* __restrict__ ob,
    float* __restrict__ dstF, float* __restrict__ sAt)
{
  constexpr int A = D / 64;
  constexpr int PITCH = D + 8;
  constexpr int KI = D / 32;
  constexpr int CT1 = D / 64;
  constexpr int CT2 = DOUT / 64;
  __shared__ alignas(16) u16 g_lds[64 * PITCH];
  __shared__ float b1_lds[D];
  __shared__ float b2_lds[DOUT];
  __shared__ int i_lds[64 * A];

  const int tid = threadIdx.x;
  const int wave = tid >> 6;
  const int lane = tid & 63;
  const int q = lane >> 4;
  const int i = lane & 15;
  const int t0 = blockIdx.x * 64;

  for (int c = tid; c < D; c += 256) b1_lds[c] = rb[c];
  for (int c = tid; c < DOUT; c += 256) b2_lds[c] = ob[c];
  if (MODE != 1)
    for (int c = tid; c < 64 * A; c += 256) i_lds[c] = idx[t0 * A + c];

  for (int c = tid; c < 64 * A * 8; c += 256) {
    int e = c >> 3, p = c & 7;
    int r = e / A, sl = e - r * A;
    uint4 val;
    if (MODE != 1) {
      int obj = idx[(t0 + r) * A + sl];
      val = pack8(srcF + (size_t)obj * 64 + p * 8);
    } else {
      if (sl == 0) val = *(const uint4*)(srcM + (size_t)(t0 + r) * 64 + p * 8);
      else         val = pack8(srcF + (size_t)(t0 + r) * 64 + p * 8);
    }
    *(uint4*)(&g_lds[r * PITCH + sl * 64 + p * 8]) = val;
  }
  __syncthreads();

  bf16x8 af[KI];
  bf16x8 b1[CT1][KI];
  #pragma unroll
  for (int j = 0; j < CT1; ++j)
    #pragma unroll
    for (int k = 0; k < KI; ++k)
      b1[j][k] = *(const bf16x8*)(rwt +
          (size_t)((wave * CT1 + j) * 16 + i) * D + k * 32 + q * 8);
  floatx4 acc1[4][CT1];
  #pragma unroll
  for (int rt = 0; rt < 4; ++rt)
    #pragma unroll
    for (int j = 0; j < CT1; ++j) acc1[rt][j] = (floatx4)0.f;
  #pragma unroll
  for (int rt = 0; rt < 4; ++rt) {
    #pragma unroll
    for (int k = 0; k < KI; ++k)
      af[k] = *(const bf16x8*)(&g_lds[(rt * 16 + i) * PITCH + k * 32 + q * 8]);
    #pragma unroll
    for (int j = 0; j < CT1; ++j)
      #pragma unroll
      for (int k = 0; k < KI; ++k)
        acc1[rt][j] = __builtin_amdgcn_mfma_f32_16x16x32_bf16(
            af[k], b1[j][k], acc1[rt][j], 0, 0, 0);
  }
  __syncthreads();
  #pragma unroll
  for (int rt = 0; rt < 4; ++rt)
    #pragma unroll
    for (int j = 0; j < CT1; ++j) {
      int col = (wave * CT1 + j) * 16 + i;
      #pragma unroll
      for (int r = 0; r < 4; ++r) {
        int row = rt * 16 + q * 4 + r;
        float h = acc1[rt][j][r] + b1_lds[col];
        float g = bf2f(g_lds[row * PITCH + col]);
        g_lds[row * PITCH + col] = f2bf(g + mish_f(h));
      }
    }
  __syncthreads();
  bf16x8 b2[CT2][KI];
  #pragma unroll
  for (int j = 0; j < CT2; ++j)
    #pragma unroll
    for (int k = 0; k < KI; ++k)
      b2[j][k] = *(const bf16x8*)(owt +
          (size_t)((wave * CT2 + j) * 16 + i) * D + k * 32 + q * 8);
  floatx4 acc2[4][CT2];
  #pragma unroll
  for (int rt = 0; rt < 4; ++rt)
    #pragma unroll
    for (int j = 0; j < CT2; ++j) acc2[rt][j] = (floatx4)0.f;
  #pragma unroll
  for (int rt = 0; rt < 4; ++rt) {
    #pragma unroll
    for (int k = 0; k < KI; ++k)
      af[k] = *(const bf16x8*)(&g_lds[(rt * 16 + i) * PITCH + k * 32 + q * 8]);
    #pragma unroll
    for (int j = 0; j < CT2; ++j)
      #pragma unroll
      for (int k = 0; k < KI; ++k)
        acc2[rt][j] = __builtin_amdgcn_mfma_f32_16x16x32_bf16(
            af[k], b2[j][k], acc2[rt][j], 0, 0, 0);
  }
  #pragma unroll
  for (int rt = 0; rt < 4; ++rt)
    #pragma unroll
    for (int j = 0; j < CT2; ++j) {
      int col = (wave * CT2 + j) * 16 + i;
      #pragma unroll
      for (int r = 0; r < 4; ++r) {
        int row = rt * 16 + q * 4 + r;
        float y = acc2[rt][j][r] + b2_lds[col];
        if (MODE == 2) {
          int slot = col >> 6, cc = col & 63;
          int obj = i_lds[row * A + slot];
          atomicAdd(&sAt[(size_t)obj * 64 + cc], __expf(fminf(12.f * y, 82.f)));
        } else {
          dstF[(size_t)(t0 + row) * 64 + col] = y;
        }
      }
    }
}

__global__ __launch_bounds__(256) void final_kernel(
    const float* __restrict__ s, const unsigned char* __restrict__ flag,
    u16* __restrict__ maxmsg)
{
  int tid = (int)threadIdx.x;
  int o = blockIdx.x * 64 + (tid >> 2);
  int c0 = (tid & 3) * 16;
  float add = flag[o] ? 1e-37f : 1e-16f;
  const float* sp = s + (size_t)o * 64 + c0;
  u16* mp = maxmsg + (size_t)o * 64 + c0;
  u16 tmp[16];
  #pragma unroll
  for (int j = 0; j < 16; ++j)
    tmp[j] = f2bf(__logf(sp[j] + add) * (1.f / 12.f));
  *(uint4*)(mp)     = *(uint4*)(tmp);
  *(uint4*)(mp + 8) = *(uint4*)(tmp + 8);
}

extern "C" void kernel_launch(void* const* d_in, const int* in_sizes, int n_in,
                              void* d_out, int out_size, void* d_ws, size_t ws_size,
                              hipStream_t stream)
{
  (void)in_sizes; (void)n_in; (void)out_size;
  const float* obj_emb = (const float*)d_in[0];
  const float* r0rb = (const float*)d_in[5];
  const float* r0ob = (const float*)d_in[7];
  const float* r1rb = (const float*)d_in[9];
  const float* r1ob = (const float*)d_in[11];
  const float* r2rb = (const float*)d_in[13];
  const float* r2ob = (const float*)d_in[15];
  const float* urb  = (const float*)d_in[17];
  const float* uob  = (const float*)d_in[19];
  float* out = (float*)d_out;
  char* ws = (char*)d_ws;

  const size_t NEED1 = 174605312ull;
  const size_t NEED2 = NEED1 + 16777216ull;

  if (ws_size >= NEED1) {
    u16* msg           = (u16*)(ws);
    u16* wt            = (u16*)(ws + 150994944ull);
    unsigned char* flg = (unsigned char*)(ws + 151273472ull);
    int* nidx          = (int*)(ws + 168181760ull);
    int* count         = (int*)(ws + 172900352ull);
    int* offsets       = (int*)(ws + 173424640ull);
    int* cursor        = (int*)(ws + 173948928ull);
    int* thrpre        = (int*)(ws + 174473216ull);
    int* blocksum      = (int*)(ws + 174604288ull);
    u16* ebf           = (u16*)(ws + 174605312ull);
    bool use_ebf = ws_size >= NEED2;

    hipMemsetAsync(count, 0, N_OBJ * 4, stream);
    hipMemsetAsync(flg, 0, N_OBJ, stream);

    if (use_ebf) ebf_kernel<<<4096, 256, 0, stream>>>(obj_emb, ebf);
    norm_kernel<<<TOTI / 256, 256, 0, stream>>>(
        (const int*)d_in[1], (const int*)d_in[2], (const int*)d_in[3],
        nidx, count, flg);
    prep_kernel<<<544, 256, 0, stream>>>(
        (const float*)d_in[4], (const float*)d_in[6], (const float*)d_in[8],
        (const float*)d_in[10], (const float*)d_in[12], (const float*)d_in[14],
        (const float*)d_in[16], (const float*)d_in[18], wt);
    scan_a<<<128, 256, 0, stream>>>(count, thrpre, blocksum);
    scan_b<<<1, 128, 0, stream>>>(blocksum);
    scan_c<<<128, 256, 0, stream>>>(count, thrpre, blocksum, offsets, cursor);

    if (use_ebf) {
      rel_merged<1><<<10240, 256, 28672, stream>>>(
          obj_emb, ebf, nidx, wt, r0rb, r0ob, r1rb, r1ob, r2rb, r2ob, msg, cursor);
      upd_fused<1><<<2048, 256, 0, stream>>>(
          obj_emb, ebf, msg, count, offsets, flg,
          wt + 114688, urb, wt + 131072, uob, out);
    } else {
      rel_merged<0><<<10240, 256, 28672, stream>>>(
          obj_emb, ebf, nidx, wt, r0rb, r0ob, r1rb, r1ob, r2rb, r2ob, msg, cursor);
      upd_fused<0><<<2048, 256, 0, stream>>>(
          obj_emb, ebf, msg, count, offsets, flg,
          wt + 114688, urb, wt + 131072, uob, out);
    }
  } else {
    // ---- fallback: fp32 atomic path ----
    float* s           = (float*)(ws);
    u16* wt            = (u16*)(ws + 33554432ull);
    unsigned char* flg = (unsigned char*)(ws + 33832960ull);
    u16* maxmsg        = (u16*)(ws + 33964032ull);
    int* nidx          = (int*)(ws + 50741248ull);

    hipMemsetAsync(s, 0, 64ull * N_OBJ * 4ull, stream);
    hipMemsetAsync(flg, 0, N_OBJ, stream);

    norm_kernel<<<TOTI / 256, 256, 0, stream>>>(
        (const int*)d_in[1], (const int*)d_in[2], (const int*)d_in[3],
        nidx, nullptr, flg);
    prep_kernel<<<544, 256, 0, stream>>>(
        (const float*)d_in[4], (const float*)d_in[6], (const float*)d_in[8],
        (const float*)d_in[10], (const float*)d_in[12], (const float*)d_in[14],
        (const float*)d_in[16], (const float*)d_in[18], wt);

    mlp_fb<64, 64, 2><<<4096, 256, 0, stream>>>(
        obj_emb, nullptr, nidx, wt + 0, r0rb, wt + 4096, r0ob, nullptr, s);
    mlp_fb<128, 128, 2><<<4096, 256, 0, stream>>>(
        obj_emb, nullptr, nidx + L0R, wt + 8192, r1rb, wt + 24576, r1ob, nullptr, s);
    mlp_fb<192, 192, 2><<<2048, 256, 0, stream>>>(
        obj_emb, nullptr, nidx + L0R + L1R, wt + 40960, r2rb, wt + 77824, r2ob,
        nullptr, s);

    final_kernel<<<N_OBJ / 64, 256, 0, stream>>>(s, flg, maxmsg);

    mlp_fb<128, 64, 1><<<2048, 256, 0, stream>>>(
        obj_emb, maxmsg, nullptr, wt + 114688, urb, wt + 131072, uob, out, nullptr);
  }
}

// Round 10
// 387.268 us; speedup vs baseline: 1.2831x; 1.0326x over previous
//
#include <hip/hip_runtime.h>
#include <stdint.h>

typedef unsigned short u16;
typedef __bf16 bf16x8 __attribute__((ext_vector_type(8)));
typedef float floatx4 __attribute__((ext_vector_type(4)));

#define N_OBJ    131072
#define L0R      262144
#define L1R      524288
#define L2R      393216
#define TOTI     (L0R + L1R + L2R)   // 1179648

// ---- full path layout (bytes), NEED2 = 191,382,528 ----
// msg @0 (150,994,944) | wt @150994944 (278,528) | flag @151273472 (131,072)
// (hole) | nidx @168181760 | count @172900352 | offsets @173424640
// cursor @173948928 | thrpre @174473216 | blocksum @174604288 | ebf @174605312
// fallback (<174.6MB): s fp32 [N][64] @0; wt @33554432; flag @33832960;
//                      maxmsg @33964032; nidx @50741248

__device__ __forceinline__ float bf2f(u16 u) {
  union { uint32_t i; float f; } v; v.i = ((uint32_t)u) << 16; return v.f;
}
__device__ __forceinline__ u16 f2bf(float f) {           // RNE (cold paths)
  union { float f; uint32_t i; } v; v.f = f;
  uint32_t r = (v.i + 0x7FFFu + ((v.i >> 16) & 1u)) >> 16;
  return (u16)r;
}
__device__ __forceinline__ u16 f2bf_t(float f) {         // truncate (hot paths)
  return (u16)(__float_as_uint(f) >> 16);
}
__device__ __forceinline__ uint4 pack8(const float* sp) {
  float4 f0 = *(const float4*)(sp);
  float4 f1 = *(const float4*)(sp + 4);
  uint4 v;
  v.x = (uint32_t)f2bf(f0.x) | ((uint32_t)f2bf(f0.y) << 16);
  v.y = (uint32_t)f2bf(f0.z) | ((uint32_t)f2bf(f0.w) << 16);
  v.z = (uint32_t)f2bf(f1.x) | ((uint32_t)f2bf(f1.y) << 16);
  v.w = (uint32_t)f2bf(f1.z) | ((uint32_t)f2bf(f1.w) << 16);
  return v;
}
// mish(x) = x*(u^2-1)/(u^2+1), u = 1+e^x ; rcp not IEEE-div (1 ULP, ok vs bf16)
__device__ __forceinline__ float mish_f(float x) {
  float t = __expf(fminf(x, 30.f));
  float u = 1.f + t; u = u * u;
  return x * (u - 1.f) * __builtin_amdgcn_rcpf(u + 1.f);
}
#define C12 17.312340490667560f   /* 12*log2(e) */

// ---------- fused pre-kernel: ebf | norm(+count+flag) | weight prep ----------
__global__ __launch_bounds__(256) void pre_kernel(
    const float* __restrict__ emb, u16* __restrict__ ebf,
    const int* __restrict__ r0, const int* __restrict__ r1,
    const int* __restrict__ r2, int* __restrict__ nidx,
    int* __restrict__ cnt, unsigned char* __restrict__ flag,
    const float* w0, const float* w1, const float* w2, const float* w3,
    const float* w4, const float* w5, const float* w6, const float* w7,
    u16* __restrict__ wt, int use_ebf)
{
  int b = blockIdx.x;
  if (b < 4096) {
    if (!use_ebf) return;
    size_t g = (size_t)b * 256 + threadIdx.x;
    *(uint4*)(ebf + g * 8) = pack8(emb + g * 8);
  } else if (b < 4096 + TOTI / 256) {
    int g = (b - 4096) * 256 + (int)threadIdx.x;
    const int* src; int off;
    if (g < L0R)            { src = r0; off = g; }
    else if (g < L0R + L1R) { src = r1; off = g - L0R; }
    else                    { src = r2; off = g - L0R - L1R; }
    int lane = (int)threadIdx.x & 63;
    int probe = src[2 * lane + 1];
    bool i64 = (__ballot(probe == 0) == ~0ull);
    int v = i64 ? src[2 * off] : src[off];
    nidx[g] = v;
    if (g < L0R) flag[v] = 1;
    atomicAdd(&cnt[v], 1);
  } else {
    int bb = b - 4096 - TOTI / 256;
    const float* srcs[8] = {w0, w1, w2, w3, w4, w5, w6, w7};
    const int fi[8]   = {64, 64, 128, 128, 192, 192, 128, 128};
    const int fo[8]   = {64, 64, 128, 128, 192, 192, 128, 64};
    const int boff[9] = {0, 16, 32, 96, 160, 304, 448, 512, 544};
    const int woff[8] = {0, 4096, 8192, 24576, 40960, 77824, 114688, 131072};
    int m = 0;
    #pragma unroll
    for (int j = 0; j < 8; ++j) if (bb >= boff[j + 1]) m = j + 1;
    int e = (bb - boff[m]) * 256 + (int)threadIdx.x;
    int k = e / fo[m];
    int n = e - k * fo[m];
    wt[woff[m] + n * fi[m] + k] = f2bf(srcs[m][e]);
  }
}

// ---------- exclusive scan of count[131072] ----------
__global__ __launch_bounds__(256) void scan_a(
    const int* __restrict__ count, int* __restrict__ thrpre,
    int* __restrict__ blocksum)
{
  int tid = (int)threadIdx.x, b = blockIdx.x;
  int o = b * 1024 + tid * 4;
  int t = count[o] + count[o + 1] + count[o + 2] + count[o + 3];
  __shared__ int sd[256];
  sd[tid] = t; __syncthreads();
  for (int off = 1; off < 256; off <<= 1) {
    int v = (tid >= off) ? sd[tid - off] : 0;
    __syncthreads();
    sd[tid] += v;
    __syncthreads();
  }
  thrpre[b * 256 + tid] = sd[tid] - t;
  if (tid == 255) blocksum[b] = sd[tid];
}
__global__ __launch_bounds__(128) void scan_b(int* __restrict__ blocksum)
{
  int tid = (int)threadIdx.x;
  int t = blocksum[tid];
  __shared__ int sd[128];
  sd[tid] = t; __syncthreads();
  for (int off = 1; off < 128; off <<= 1) {
    int v = (tid >= off) ? sd[tid - off] : 0;
    __syncthreads();
    sd[tid] += v;
    __syncthreads();
  }
  blocksum[tid] = sd[tid] - t;
}
__global__ __launch_bounds__(256) void scan_c(
    const int* __restrict__ count, const int* __restrict__ thrpre,
    const int* __restrict__ blocksum, int* __restrict__ offsets,
    int* __restrict__ cursor)
{
  int tid = (int)threadIdx.x, b = blockIdx.x;
  int o = b * 1024 + tid * 4;
  int base = blocksum[b] + thrpre[b * 256 + tid];
  #pragma unroll
  for (int j = 0; j < 4; ++j) {
    offsets[o + j] = base;
    cursor[o + j] = base;
    base += count[o + j];
  }
}

// ---------- relation MLP body (CSR msg write), dynamic-LDS carve ----------
template<int D, int DOUT, int EBF>
__device__ __forceinline__ void mlp_body(
    char* smem, const float* __restrict__ srcF, const u16* __restrict__ srcB,
    const int* __restrict__ idx, int bidx,
    const u16* __restrict__ rwt, const float* __restrict__ rb,
    const u16* __restrict__ owt, const float* __restrict__ ob,
    u16* __restrict__ msg, int* __restrict__ cursor)
{
  constexpr int A = D / 64;
  constexpr int PITCH = D + 8;
  constexpr int KI = D / 32;
  constexpr int CT1 = D / 64;
  constexpr int CT2 = DOUT / 64;
  u16*   g_lds  = (u16*)smem;
  float* b1_lds = (float*)(smem + 64 * PITCH * 2);
  float* b2_lds = b1_lds + D;
  int*   i_lds  = (int*)(b2_lds + DOUT);
  int*   p_lds  = i_lds + 64 * A;

  const int tid = threadIdx.x;
  const int wave = tid >> 6;
  const int lane = tid & 63;
  const int q = lane >> 4;
  const int i = lane & 15;
  const int t0 = bidx * 64;

  for (int c = tid; c < D; c += 256) b1_lds[c] = rb[c];
  for (int c = tid; c < DOUT; c += 256) b2_lds[c] = ob[c] * C12;  // pre-scaled
  for (int c = tid; c < 64 * A; c += 256) {
    int obj = idx[t0 * A + c];
    i_lds[c] = obj;
    p_lds[c] = atomicAdd(&cursor[obj], 1);
  }

  for (int c = tid; c < 64 * A * 8; c += 256) {
    int e = c >> 3, p = c & 7;
    int r = e / A, sl = e - r * A;
    int obj = idx[(t0 + r) * A + sl];
    uint4 val = EBF ? *(const uint4*)(srcB + (size_t)obj * 64 + p * 8)
                    : pack8(srcF + (size_t)obj * 64 + p * 8);
    *(uint4*)(&g_lds[r * PITCH + sl * 64 + p * 8]) = val;
  }
  __syncthreads();

  bf16x8 af[KI];

  // phase 1
  bf16x8 b1[CT1][KI];
  #pragma unroll
  for (int j = 0; j < CT1; ++j)
    #pragma unroll
    for (int k = 0; k < KI; ++k)
      b1[j][k] = *(const bf16x8*)(rwt +
          (size_t)((wave * CT1 + j) * 16 + i) * D + k * 32 + q * 8);

  floatx4 acc1[4][CT1];
  #pragma unroll
  for (int rt = 0; rt < 4; ++rt)
    #pragma unroll
    for (int j = 0; j < CT1; ++j) acc1[rt][j] = (floatx4)0.f;

  #pragma unroll
  for (int rt = 0; rt < 4; ++rt) {
    #pragma unroll
    for (int k = 0; k < KI; ++k)
      af[k] = *(const bf16x8*)(&g_lds[(rt * 16 + i) * PITCH + k * 32 + q * 8]);
    #pragma unroll
    for (int j = 0; j < CT1; ++j)
      #pragma unroll
      for (int k = 0; k < KI; ++k)
        acc1[rt][j] = __builtin_amdgcn_mfma_f32_16x16x32_bf16(
            af[k], b1[j][k], acc1[rt][j], 0, 0, 0);
  }
  __syncthreads();

  // epilogue 1: a2 = g + mish(h), trunc-bf16, in place
  #pragma unroll
  for (int rt = 0; rt < 4; ++rt)
    #pragma unroll
    for (int j = 0; j < CT1; ++j) {
      int col = (wave * CT1 + j) * 16 + i;
      #pragma unroll
      for (int r = 0; r < 4; ++r) {
        int row = rt * 16 + q * 4 + r;
        float h = acc1[rt][j][r] + b1_lds[col];
        float g = bf2f(g_lds[row * PITCH + col]);
        g_lds[row * PITCH + col] = f2bf_t(g + mish_f(h));
      }
    }
  __syncthreads();

  // phase 2
  bf16x8 b2[CT2][KI];
  #pragma unroll
  for (int j = 0; j < CT2; ++j)
    #pragma unroll
    for (int k = 0; k < KI; ++k)
      b2[j][k] = *(const bf16x8*)(owt +
          (size_t)((wave * CT2 + j) * 16 + i) * D + k * 32 + q * 8);

  floatx4 acc2[4][CT2];
  #pragma unroll
  for (int rt = 0; rt < 4; ++rt)
    #pragma unroll
    for (int j = 0; j < CT2; ++j) acc2[rt][j] = (floatx4)0.f;

  #pragma unroll
  for (int rt = 0; rt < 4; ++rt) {
    #pragma unroll
    for (int k = 0; k < KI; ++k)
      af[k] = *(const bf16x8*)(&g_lds[(rt * 16 + i) * PITCH + k * 32 + q * 8]);
    #pragma unroll
    for (int j = 0; j < CT2; ++j)
      #pragma unroll
      for (int k = 0; k < KI; ++k)
        acc2[rt][j] = __builtin_amdgcn_mfma_f32_16x16x32_bf16(
            af[k], b2[j][k], acc2[rt][j], 0, 0, 0);
  }
  __syncthreads();   // all phase-2 g_lds reads done before Y overwrite

  // epilogue 2: e = exp2(C12*acc + b2s) into g_lds (cheap scalar), then
  // cooperative full-row copy-out (4 wide stores/thread vs 32 scalar)
  #pragma unroll
  for (int rt = 0; rt < 4; ++rt)
    #pragma unroll
    for (int j = 0; j < CT2; ++j) {
      int col = (wave * CT2 + j) * 16 + i;
      #pragma unroll
      for (int r = 0; r < 4; ++r) {
        int row = rt * 16 + q * 4 + r;
        float z = fminf(fmaf(acc2[rt][j][r], C12, b2_lds[col]), 118.f);
        g_lds[row * PITCH + col] = f2bf_t(exp2f(z));
      }
    }
  __syncthreads();
  for (int c = tid; c < 64 * A * 8; c += 256) {
    int e = c >> 3, p = c & 7;
    int r = e / A, sl = e - r * A;
    int pos = p_lds[r * A + sl];
    *(uint4*)(msg + (size_t)pos * 64 + p * 8) =
        *(const uint4*)(&g_lds[r * PITCH + sl * 64 + p * 8]);
  }
}

// ---------- merged relation kernel, interleaved 2:2:1 block mapping ----------
template<int EBF>
__global__ __launch_bounds__(256, 3) void rel_merged(
    const float* __restrict__ srcF, const u16* __restrict__ ebf,
    const int* __restrict__ nidx, const u16* __restrict__ wt,
    const float* __restrict__ r0rb, const float* __restrict__ r0ob,
    const float* __restrict__ r1rb, const float* __restrict__ r1ob,
    const float* __restrict__ r2rb, const float* __restrict__ r2ob,
    u16* __restrict__ msg, int* __restrict__ cursor)
{
  extern __shared__ char smem[];
  int b = blockIdx.x;
  int g5 = b / 5, m = b - g5 * 5;   // heavy/light mixed through the dispatch
  if (m < 2)
    mlp_body<64, 64, EBF>(smem, srcF, ebf, nidx, g5 * 2 + m,
                          wt + 0, r0rb, wt + 4096, r0ob, msg, cursor);
  else if (m < 4)
    mlp_body<128, 128, EBF>(smem, srcF, ebf, nidx + L0R, g5 * 2 + (m - 2),
                            wt + 8192, r1rb, wt + 24576, r1ob, msg, cursor);
  else
    mlp_body<192, 192, EBF>(smem, srcF, ebf, nidx + L0R + L1R, g5,
                            wt + 40960, r2rb, wt + 77824, r2ob, msg, cursor);
}

// ---------- fused update kernel: inline CSR logsumexp + MLP -> d_out ----------
template<int EBF>
__global__ __launch_bounds__(256, 4) void upd_fused(
    const float* __restrict__ srcF, const u16* __restrict__ ebf,
    const u16* __restrict__ msg, const int* __restrict__ count,
    const int* __restrict__ offsets, const unsigned char* __restrict__ flag,
    const u16* __restrict__ rwt, const float* __restrict__ rb,
    const u16* __restrict__ owt, const float* __restrict__ ob,
    float* __restrict__ dstF)
{
  constexpr int D = 128, DOUT = 64;
  constexpr int PITCH = D + 8;
  constexpr int KI = D / 32;
  constexpr int CT1 = 2, CT2 = 1;
  __shared__ alignas(16) u16 g_lds[64 * PITCH];
  __shared__ float b1_lds[D];
  __shared__ float b2_lds[DOUT];

  const int tid = threadIdx.x;
  const int wave = tid >> 6;
  const int lane = tid & 63;
  const int q = lane >> 4;
  const int i = lane & 15;
  const int t0 = blockIdx.x * 64;

  for (int c = tid; c < D; c += 256) b1_lds[c] = rb[c];
  for (int c = tid; c < DOUT; c += 256) b2_lds[c] = ob[c];

  for (int c = tid; c < 64 * 2 * 8; c += 256) {
    int e = c >> 3, p = c & 7;
    int r = e >> 1, sl = e & 1;
    int o = t0 + r;
    if (sl == 0) {
      int deg = count[o], st = offsets[o];
      const u16* bp = msg + (size_t)st * 64 + p * 8;
      float s[8] = {0.f, 0.f, 0.f, 0.f, 0.f, 0.f, 0.f, 0.f};
      for (int j = 0; j < deg; ++j) {
        union { uint4 v; u16 a[8]; } ld;
        ld.v = *(const uint4*)(bp + (size_t)j * 64);
        #pragma unroll
        for (int k = 0; k < 8; ++k) s[k] += bf2f(ld.a[k]);
      }
      float add = flag[o] ? 1e-37f : 1e-16f;
      u16 tmp[8];
      #pragma unroll
      for (int k = 0; k < 8; ++k)
        tmp[k] = f2bf(__logf(s[k] + add) * (1.f / 12.f));
      *(uint4*)(&g_lds[r * PITCH + p * 8]) = *(uint4*)tmp;
    } else {
      uint4 val = EBF ? *(const uint4*)(ebf + (size_t)o * 64 + p * 8)
                      : pack8(srcF + (size_t)o * 64 + p * 8);
      *(uint4*)(&g_lds[r * PITCH + 64 + p * 8]) = val;
    }
  }
  __syncthreads();

  bf16x8 af[KI];
  bf16x8 b1[CT1][KI];
  #pragma unroll
  for (int j = 0; j < CT1; ++j)
    #pragma unroll
    for (int k = 0; k < KI; ++k)
      b1[j][k] = *(const bf16x8*)(rwt +
          (size_t)((wave * CT1 + j) * 16 + i) * D + k * 32 + q * 8);

  floatx4 acc1[4][CT1];
  #pragma unroll
  for (int rt = 0; rt < 4; ++rt)
    #pragma unroll
    for (int j = 0; j < CT1; ++j) acc1[rt][j] = (floatx4)0.f;

  #pragma unroll
  for (int rt = 0; rt < 4; ++rt) {
    #pragma unroll
    for (int k = 0; k < KI; ++k)
      af[k] = *(const bf16x8*)(&g_lds[(rt * 16 + i) * PITCH + k * 32 + q * 8]);
    #pragma unroll
    for (int j = 0; j < CT1; ++j)
      #pragma unroll
      for (int k = 0; k < KI; ++k)
        acc1[rt][j] = __builtin_amdgcn_mfma_f32_16x16x32_bf16(
            af[k], b1[j][k], acc1[rt][j], 0, 0, 0);
  }
  __syncthreads();

  #pragma unroll
  for (int rt = 0; rt < 4; ++rt)
    #pragma unroll
    for (int j = 0; j < CT1; ++j) {
      int col = (wave * CT1 + j) * 16 + i;
      #pragma unroll
      for (int r = 0; r < 4; ++r) {
        int row = rt * 16 + q * 4 + r;
        float h = acc1[rt][j][r] + b1_lds[col];
        float g = bf2f(g_lds[row * PITCH + col]);
        g_lds[row * PITCH + col] = f2bf_t(g + mish_f(h));
      }
    }
  __syncthreads();

  bf16x8 b2[CT2][KI];
  #pragma unroll
  for (int j = 0; j < CT2; ++j)
    #pragma unroll
    for (int k = 0; k < KI; ++k)
      b2[j][k] = *(const bf16x8*)(owt +
          (size_t)((wave * CT2 + j) * 16 + i) * D + k * 32 + q * 8);

  floatx4 acc2[4][CT2];
  #pragma unroll
  for (int rt = 0; rt < 4; ++rt)
    #pragma unroll
    for (int j = 0; j < CT2; ++j) acc2[rt][j] = (floatx4)0.f;

  #pragma unroll
  for (int rt = 0; rt < 4; ++rt) {
    #pragma unroll
    for (int k = 0; k < KI; ++k)
      af[k] = *(const bf16x8*)(&g_lds[(rt * 16 + i) * PITCH + k * 32 + q * 8]);
    #pragma unroll
    for (int j = 0; j < CT2; ++j)
      #pragma unroll
      for (int k = 0; k < KI; ++k)
        acc2[rt][j] = __builtin_amdgcn_mfma_f32_16x16x32_bf16(
            af[k], b2[j][k], acc2[rt][j], 0, 0, 0);
  }

  #pragma unroll
  for (int rt = 0; rt < 4; ++rt) {
    int col = wave * 16 + i;
    #pragma unroll
    for (int r = 0; r < 4; ++r) {
      int row = rt * 16 + q * 4 + r;
      dstF[(size_t)(t0 + row) * 64 + col] = acc2[rt][0][r] + b2_lds[col];
    }
  }
}

// ================= fallback kernels (fp32 atomic path) =================
template<int D, int DOUT, int MODE>
__global__ __launch_bounds__(256, (D >= 192) ? 3 : 4) void mlp_fb(
    const float* __restrict__ srcF, const u16* __restrict__ srcM,
    const int* __restrict__ idx,
    const u16* __restrict__ rwt, const float* __restrict__ rb,
    const u16* __restrict__ owt, const float* __restrict__ ob,
    float* __restrict__ dstF, float* __restrict__ sAt)
{
  constexpr int A = D / 64;
  constexpr int PITCH = D + 8;
  constexpr int KI = D / 32;
  constexpr int CT1 = D / 64;
  constexpr int CT2 = DOUT / 64;
  __shared__ alignas(16) u16 g_lds[64 * PITCH];
  __shared__ float b1_lds[D];
  __shared__ float b2_lds[DOUT];
  __shared__ int i_lds[64 * A];

  const int tid = threadIdx.x;
  const int wave = tid >> 6;
  const int lane = tid & 63;
  const int q = lane >> 4;
  const int i = lane & 15;
  const int t0 = blockIdx.x * 64;

  for (int c = tid; c < D; c += 256) b1_lds[c] = rb[c];
  for (int c = tid; c < DOUT; c += 256) b2_lds[c] = ob[c];
  if (MODE != 1)
    for (int c = tid; c < 64 * A; c += 256) i_lds[c] = idx[t0 * A + c];

  for (int c = tid; c < 64 * A * 8; c += 256) {
    int e = c >> 3, p = c & 7;
    int r = e / A, sl = e - r * A;
    uint4 val;
    if (MODE != 1) {
      int obj = idx[(t0 + r) * A + sl];
      val = pack8(srcF + (size_t)obj * 64 + p * 8);
    } else {
      if (sl == 0) val = *(const uint4*)(srcM + (size_t)(t0 + r) * 64 + p * 8);
      else         val = pack8(srcF + (size_t)(t0 + r) * 64 + p * 8);
    }
    *(uint4*)(&g_lds[r * PITCH + sl * 64 + p * 8]) = val;
  }
  __syncthreads();

  bf16x8 af[KI];
  bf16x8 b1[CT1][KI];
  #pragma unroll
  for (int j = 0; j < CT1; ++j)
    #pragma unroll
    for (int k = 0; k < KI; ++k)
      b1[j][k] = *(const bf16x8*)(rwt +
          (size_t)((wave * CT1 + j) * 16 + i) * D + k * 32 + q * 8);
  floatx4 acc1[4][CT1];
  #pragma unroll
  for (int rt = 0; rt < 4; ++rt)
    #pragma unroll
    for (int j = 0; j < CT1; ++j) acc1[rt][j] = (floatx4)0.f;
  #pragma unroll
  for (int rt = 0; rt < 4; ++rt) {
    #pragma unroll
    for (int k = 0; k < KI; ++k)
      af[k] = *(const bf16x8*)(&g_lds[(rt * 16 + i) * PITCH + k * 32 + q * 8]);
    #pragma unroll
    for (int j = 0; j < CT1; ++j)
      #pragma unroll
      for (int k = 0; k < KI; ++k)
        acc1[rt][j] = __builtin_amdgcn_mfma_f32_16x16x32_bf16(
            af[k], b1[j][k], acc1[rt][j], 0, 0, 0);
  }
  __syncthreads();
  #pragma unroll
  for (int rt = 0; rt < 4; ++rt)
    #pragma unroll
    for (int j = 0; j < CT1; ++j) {
      int col = (wave * CT1 + j) * 16 + i;
      #pragma unroll
      for (int r = 0; r < 4; ++r) {
        int row = rt * 16 + q * 4 + r;
        float h = acc1[rt][j][r] + b1_lds[col];
        float g = bf2f(g_lds[row * PITCH + col]);
        g_lds[row * PITCH + col] = f2bf(g + mish_f(h));
      }
    }
  __syncthreads();
  bf16x8 b2[CT2][KI];
  #pragma unroll
  for (int j = 0; j < CT2; ++j)
    #pragma unroll
    for (int k = 0; k < KI; ++k)
      b2[j][k] = *(const bf16x8*)(owt +
          (size_t)((wave * CT2 + j) * 16 + i) * D + k * 32 + q * 8);
  floatx4 acc2[4][CT2];
  #pragma unroll
  for (int rt = 0; rt < 4; ++rt)
    #pragma unroll
    for (int j = 0; j < CT2; ++j) acc2[rt][j] = (floatx4)0.f;
  #pragma unroll
  for (int rt = 0; rt < 4; ++rt) {
    #pragma unroll
    for (int k = 0; k < KI; ++k)
      af[k] = *(const bf16x8*)(&g_lds[(rt * 16 + i) * PITCH + k * 32 + q * 8]);
    #pragma unroll
    for (int j = 0; j < CT2; ++j)
      #pragma unroll
      for (int k = 0; k < KI; ++k)
        acc2[rt][j] = __builtin_amdgcn_mfma_f32_16x16x32_bf16(
            af[k], b2[j][k], acc2[rt][j], 0, 0, 0);
  }
  #pragma unroll
  for (int rt = 0; rt < 4; ++rt)
    #pragma unroll
    for (int j = 0; j < CT2; ++j) {
      int col = (wave * CT2 + j) * 16 + i;
      #pragma unroll
      for (int r = 0; r < 4; ++r) {
        int row = rt * 16 + q * 4 + r;
        float y = acc2[rt][j][r] + b2_lds[col];
        if (MODE == 2) {
          int slot = col >> 6, cc = col & 63;
          int obj = i_lds[row * A + slot];
          atomicAdd(&sAt[(size_t)obj * 64 + cc], __expf(fminf(12.f * y, 82.f)));
        } else {
          dstF[(size_t)(t0 + row) * 64 + col] = y;
        }
      }
    }
}

__global__ __launch_bounds__(256) void norm_fb(
    const int* __restrict__ r0, const int* __restrict__ r1,
    const int* __restrict__ r2, int* __restrict__ n,
    unsigned char* __restrict__ flag)
{
  int g = blockIdx.x * 256 + (int)threadIdx.x;
  const int* src; int off;
  if (g < L0R)            { src = r0; off = g; }
  else if (g < L0R + L1R) { src = r1; off = g - L0R; }
  else                    { src = r2; off = g - L0R - L1R; }
  int lane = (int)threadIdx.x & 63;
  int probe = src[2 * lane + 1];
  bool i64 = (__ballot(probe == 0) == ~0ull);
  int v = i64 ? src[2 * off] : src[off];
  n[g] = v;
  if (g < L0R) flag[v] = 1;
}

__global__ __launch_bounds__(256) void prep_fb(
    const float* w0, const float* w1, const float* w2, const float* w3,
    const float* w4, const float* w5, const float* w6, const float* w7,
    u16* __restrict__ wt)
{
  int b = blockIdx.x;
  const float* srcs[8] = {w0, w1, w2, w3, w4, w5, w6, w7};
  const int fi[8]   = {64, 64, 128, 128, 192, 192, 128, 128};
  const int fo[8]   = {64, 64, 128, 128, 192, 192, 128, 64};
  const int boff[9] = {0, 16, 32, 96, 160, 304, 448, 512, 544};
  const int woff[8] = {0, 4096, 8192, 24576, 40960, 77824, 114688, 131072};
  int m = 0;
  #pragma unroll
  for (int j = 0; j < 8; ++j) if (b >= boff[j + 1]) m = j + 1;
  int e = (b - boff[m]) * 256 + (int)threadIdx.x;
  int k = e / fo[m];
  int n = e - k * fo[m];
  wt[woff[m] + n * fi[m] + k] = f2bf(srcs[m][e]);
}

__global__ __launch_bounds__(256) void final_kernel(
    const float* __restrict__ s, const unsigned char* __restrict__ flag,
    u16* __restrict__ maxmsg)
{
  int tid = (int)threadIdx.x;
  int o = blockIdx.x * 64 + (tid >> 2);
  int c0 = (tid & 3) * 16;
  float add = flag[o] ? 1e-37f : 1e-16f;
  const float* sp = s + (size_t)o * 64 + c0;
  u16* mp = maxmsg + (size_t)o * 64 + c0;
  u16 tmp[16];
  #pragma unroll
  for (int j = 0; j < 16; ++j)
    tmp[j] = f2bf(__logf(sp[j] + add) * (1.f / 12.f));
  *(uint4*)(mp)     = *(uint4*)(tmp);
  *(uint4*)(mp + 8) = *(uint4*)(tmp + 8);
}

extern "C" void kernel_launch(void* const* d_in, const int* in_sizes, int n_in,
                              void* d_out, int out_size, void* d_ws, size_t ws_size,
                              hipStream_t stream)
{
  (void)in_sizes; (void)n_in; (void)out_size;
  const float* obj_emb = (const float*)d_in[0];
  const float* r0rb = (const float*)d_in[5];
  const float* r0ob = (const float*)d_in[7];
  const float* r1rb = (const float*)d_in[9];
  const float* r1ob = (const float*)d_in[11];
  const float* r2rb = (const float*)d_in[13];
  const float* r2ob = (const float*)d_in[15];
  const float* urb  = (const float*)d_in[17];
  const float* uob  = (const float*)d_in[19];
  float* out = (float*)d_out;
  char* ws = (char*)d_ws;

  const size_t NEED1 = 174605312ull;
  const size_t NEED2 = NEED1 + 16777216ull;

  if (ws_size >= NEED1) {
    u16* msg           = (u16*)(ws);
    u16* wt            = (u16*)(ws + 150994944ull);
    unsigned char* flg = (unsigned char*)(ws + 151273472ull);
    int* nidx          = (int*)(ws + 168181760ull);
    int* count         = (int*)(ws + 172900352ull);
    int* offsets       = (int*)(ws + 173424640ull);
    int* cursor        = (int*)(ws + 173948928ull);
    int* thrpre        = (int*)(ws + 174473216ull);
    int* blocksum      = (int*)(ws + 174604288ull);
    u16* ebf           = (u16*)(ws + 174605312ull);
    int use_ebf = (ws_size >= NEED2) ? 1 : 0;

    hipMemsetAsync(count, 0, N_OBJ * 4, stream);
    hipMemsetAsync(flg, 0, N_OBJ, stream);

    pre_kernel<<<4096 + TOTI / 256 + 544, 256, 0, stream>>>(
        obj_emb, ebf,
        (const int*)d_in[1], (const int*)d_in[2], (const int*)d_in[3],
        nidx, count, flg,
        (const float*)d_in[4], (const float*)d_in[6], (const float*)d_in[8],
        (const float*)d_in[10], (const float*)d_in[12], (const float*)d_in[14],
        (const float*)d_in[16], (const float*)d_in[18], wt, use_ebf);
    scan_a<<<128, 256, 0, stream>>>(count, thrpre, blocksum);
    scan_b<<<1, 128, 0, stream>>>(blocksum);
    scan_c<<<128, 256, 0, stream>>>(count, thrpre, blocksum, offsets, cursor);

    if (use_ebf) {
      rel_merged<1><<<10240, 256, 28672, stream>>>(
          obj_emb, ebf, nidx, wt, r0rb, r0ob, r1rb, r1ob, r2rb, r2ob, msg, cursor);
      upd_fused<1><<<2048, 256, 0, stream>>>(
          obj_emb, ebf, msg, count, offsets, flg,
          wt + 114688, urb, wt + 131072, uob, out);
    } else {
      rel_merged<0><<<10240, 256, 28672, stream>>>(
          obj_emb, ebf, nidx, wt, r0rb, r0ob, r1rb, r1ob, r2rb, r2ob, msg, cursor);
      upd_fused<0><<<2048, 256, 0, stream>>>(
          obj_emb, ebf, msg, count, offsets, flg,
          wt + 114688, urb, wt + 131072, uob, out);
    }
  } else {
    float* s           = (float*)(ws);
    u16* wt            = (u16*)(ws + 33554432ull);
    unsigned char* flg = (unsigned char*)(ws + 33832960ull);
    u16* maxmsg        = (u16*)(ws + 33964032ull);
    int* nidx          = (int*)(ws + 50741248ull);

    hipMemsetAsync(s, 0, 64ull * N_OBJ * 4ull, stream);
    hipMemsetAsync(flg, 0, N_OBJ, stream);

    norm_fb<<<TOTI / 256, 256, 0, stream>>>(
        (const int*)d_in[1], (const int*)d_in[2], (const int*)d_in[3], nidx, flg);
    prep_fb<<<544, 256, 0, stream>>>(
        (const float*)d_in[4], (const float*)d_in[6], (const float*)d_in[8],
        (const float*)d_in[10], (const float*)d_in[12], (const float*)d_in[14],
        (const float*)d_in[16], (const float*)d_in[18], wt);

    mlp_fb<64, 64, 2><<<4096, 256, 0, stream>>>(
        obj_emb, nullptr, nidx, wt + 0, r0rb, wt + 4096, r0ob, nullptr, s);
    mlp_fb<128, 128, 2><<<4096, 256, 0, stream>>>(
        obj_emb, nullptr, nidx + L0R, wt + 8192, r1rb, wt + 24576, r1ob, nullptr, s);
    mlp_fb<192, 192, 2><<<2048, 256, 0, stream>>>(
        obj_emb, nullptr, nidx + L0R + L1R, wt + 40960, r2rb, wt + 77824, r2ob,
        nullptr, s);

    final_kernel<<<N_OBJ / 64, 256, 0, stream>>>(s, flg, maxmsg);

    mlp_fb<128, 64, 1><<<2048, 256, 0, stream>>>(
        obj_emb, maxmsg, nullptr, wt + 114688, urb, wt + 131072, uob, out, nullptr);
  }
}